// Round 4
// baseline (3407.844 us; speedup 1.0000x reference)
//
#include <hip/hip_runtime.h>
#include <math.h>

#define CIN 256
#define COUT 256
#define SD 512
#define NB 16
#define KSCALE (1.0f / 48.0f)   // 1/sqrt(256*9)
#define MEPS 1e-8f

// ---------------- modulation: s and demod for all 4 layers ----------------
__global__ __launch_bounds__(256) void mod_k(
    const float* __restrict__ style,   // (B,512)
    const float* __restrict__ weights, // (4,256,256,3)
    const float* __restrict__ mod_w,   // (4,256,512)
    const float* __restrict__ mod_b,   // (4,256)
    float* __restrict__ s_all,         // (4,B,256)
    float* __restrict__ demod_all)     // (4,B,256)
{
    int layer = blockIdx.x >> 4;
    int b = blockIdx.x & 15;
    int t = threadIdx.x;               // 0..255
    __shared__ float st[SD];
    __shared__ float s2[CIN];

    for (int j = t; j < SD; j += 256) st[j] = style[b * SD + j];
    __syncthreads();

    // s[b, ci=t] = sum_j style[b,j] * mod_w[layer, t, j] + mod_b[layer, t]
    const float* mw = mod_w + ((size_t)layer * CIN + t) * SD;
    float acc = 0.f;
    for (int j = 0; j < SD; ++j) acc += mw[j] * st[j];
    float s = acc + mod_b[layer * CIN + t];
    s_all[((size_t)layer * NB + b) * CIN + t] = s;
    s2[t] = s * s;
    __syncthreads();

    // demod[b, a=t] = rsqrt(SCALE^2 * sum_{j,k} w[a,j,k]^2 s[j]^2 + eps)
    const float* wr = weights + ((size_t)layer * COUT + t) * (CIN * 3);
    float d = 0.f;
    for (int ci = 0; ci < CIN; ++ci) {
        float w0 = wr[ci * 3 + 0];
        float w1 = wr[ci * 3 + 1];
        float w2 = wr[ci * 3 + 2];
        d += (w0 * w0 + w1 * w1 + w2 * w2) * s2[ci];
    }
    demod_all[((size_t)layer * NB + b) * CIN + t] =
        rsqrtf(KSCALE * KSCALE * d + MEPS);
}

// ---------------- same conv: out[co,l] = dm[co]*SCALE*sum_{ci,k} w[co,ci,k]*s[ci]*x[ci,l+k-1] + bias
__global__ __launch_bounds__(256) void conv_same_k(
    const float* __restrict__ in, int L, int inRS,
    const float* __restrict__ w,      // (256,256,3) layer base
    const float* __restrict__ s,      // (b,256) group base
    const float* __restrict__ demod,  // (b,256) group base
    const float* __restrict__ bias,   // (256) layer base
    float* __restrict__ outp, int outRS)
{
    __shared__ float xs[32][68];
    __shared__ float ws[32][3][64];
    int lt = blockIdx.x * 64;
    int cot = blockIdx.y * 64;
    int b = blockIdx.z;
    int t = threadIdx.x;
    int lq = t & 15;
    int cq = t >> 4;

    float acc[4][4] = {};
    const float* xb = in + (size_t)b * CIN * inRS;
    const float* sb = s + b * CIN;

    for (int ci0 = 0; ci0 < CIN; ci0 += 32) {
        __syncthreads();
        for (int idx = t; idx < 32 * 66; idx += 256) {
            int ci = idx / 66, j = idx % 66;       // xs[ci][j] = s*x[lt-1+j]
            int gl = lt - 1 + j;
            float v = (gl >= 0 && gl < L) ? xb[(size_t)(ci0 + ci) * inRS + gl] : 0.f;
            xs[ci][j] = v * sb[ci0 + ci];
        }
        for (int idx = t; idx < 32 * 192; idx += 256) {
            int ci = idx / 192, rem = idx % 192;
            int k = rem >> 6, co = rem & 63;
            ws[ci][k][co] = w[((size_t)(cot + co) * CIN + ci0 + ci) * 3 + k];
        }
        __syncthreads();
        for (int ci = 0; ci < 32; ++ci) {
            float xv[6];
            #pragma unroll
            for (int i = 0; i < 6; ++i) xv[i] = xs[ci][lq * 4 + i];
            #pragma unroll
            for (int k = 0; k < 3; ++k)
                #pragma unroll
                for (int cc = 0; cc < 4; ++cc) {
                    float wv = ws[ci][k][cq * 4 + cc];
                    #pragma unroll
                    for (int jj = 0; jj < 4; ++jj)
                        acc[cc][jj] += wv * xv[jj + k];
                }
        }
    }
    float* ob = outp + (size_t)b * COUT * outRS;
    #pragma unroll
    for (int cc = 0; cc < 4; ++cc) {
        int co = cot + cq * 4 + cc;
        float dm = demod[b * COUT + co] * KSCALE;
        float bi = bias[co];
        #pragma unroll
        for (int jj = 0; jj < 4; ++jj)
            ob[(size_t)co * outRS + lt + lq * 4 + jj] = acc[cc][jj] * dm + bi;
    }
}

// ---------------- transpose conv stride 2 (JAX double-transpose semantics) ----------
// out[o,n] = s[o] * sum_{c,k: n=2m+k} SCALE*demod[c]*w[c,o,k]*x[c,m] + bias[o]
__global__ __launch_bounds__(256) void upconv_k(
    const float* __restrict__ in, int Lin, int inRS,
    const float* __restrict__ w,       // (256,256,3): indexed w[c, o, k]
    const float* __restrict__ s,       // (b,256): output-channel scale
    const float* __restrict__ demod,   // (b,256): input-channel scale
    const float* __restrict__ bias,
    float* __restrict__ outp, int outRS, int Lout)
{
    __shared__ float xs[32][36];
    __shared__ float ws[32][3][64];
    int nt = blockIdx.x * 64;
    int m0 = nt >> 1;
    int cot = blockIdx.y * 64;
    int b = blockIdx.z;
    int t = threadIdx.x;
    int lq = t & 15;
    int cq = t >> 4;

    float acc[4][4] = {};
    const float* xb = in + (size_t)b * CIN * inRS;
    const float* db = demod + b * CIN;

    for (int ci0 = 0; ci0 < CIN; ci0 += 32) {
        __syncthreads();
        for (int idx = t; idx < 32 * 34; idx += 256) {
            int ci = idx / 34, j = idx % 34;       // xs[ci][j] = KSCALE*demod[c]*x[m0-1+j]
            int gl = m0 - 1 + j;
            float v = (gl >= 0 && gl < Lin) ? xb[(size_t)(ci0 + ci) * inRS + gl] : 0.f;
            xs[ci][j] = v * db[ci0 + ci] * KSCALE;
        }
        for (int idx = t; idx < 32 * 192; idx += 256) {
            int ci = idx / 192, rem = idx % 192;
            int k = rem >> 6, co = rem & 63;
            // w[c, o, k] with c = ci0+ci (contracted), o = cot+co (output)
            ws[ci][k][co] = w[((size_t)(ci0 + ci) * CIN + (cot + co)) * 3 + k];
        }
        __syncthreads();
        for (int ci = 0; ci < 32; ++ci) {
            float xm1 = xs[ci][2 * lq];        // x[m0 + 2lq - 1]
            float x0  = xs[ci][2 * lq + 1];    // x[m0 + 2lq]
            float xp1 = xs[ci][2 * lq + 2];    // x[m0 + 2lq + 1]
            #pragma unroll
            for (int cc = 0; cc < 4; ++cc) {
                float w0 = ws[ci][0][cq * 4 + cc];
                float w1 = ws[ci][1][cq * 4 + cc];
                float w2 = ws[ci][2][cq * 4 + cc];
                acc[cc][0] += w0 * x0 + w2 * xm1;   // n = nt+4lq   (even)
                acc[cc][1] += w1 * x0;              // n+1          (odd)
                acc[cc][2] += w0 * xp1 + w2 * x0;   // n+2          (even)
                acc[cc][3] += w1 * xp1;             // n+3          (odd)
            }
        }
    }
    float* ob = outp + (size_t)b * COUT * outRS;
    #pragma unroll
    for (int cc = 0; cc < 4; ++cc) {
        int co = cot + cq * 4 + cc;
        float os = s[b * COUT + co];      // output-channel modulation
        float bi = bias[co];
        #pragma unroll
        for (int jj = 0; jj < 4; ++jj) {
            int n = nt + lq * 4 + jj;
            if (n < Lout)
                ob[(size_t)co * outRS + n] = acc[cc][jj] * os + bi;
        }
    }
}

// ---------------- stride-2 valid conv: out[l] = dm[co]*SCALE*sum w[co,ci,k]*s[ci]*xb[ci,2l+k] + bias
__global__ __launch_bounds__(256) void conv_down_k(
    const float* __restrict__ in, int Lin, int inRS,
    const float* __restrict__ w,
    const float* __restrict__ s,
    const float* __restrict__ demod,
    const float* __restrict__ bias,
    float* __restrict__ outp, int outRS)
{
    __shared__ float xs[32][132];
    __shared__ float ws[32][3][64];
    int lt = blockIdx.x * 64;
    int cot = blockIdx.y * 64;
    int b = blockIdx.z;
    int t = threadIdx.x;
    int lq = t & 15;
    int cq = t >> 4;

    float acc[4][4] = {};
    const float* xb = in + (size_t)b * CIN * inRS;
    const float* sb = s + b * CIN;

    for (int ci0 = 0; ci0 < CIN; ci0 += 32) {
        __syncthreads();
        for (int idx = t; idx < 32 * 130; idx += 256) {
            int ci = idx / 130, j = idx % 130;     // xs[ci][j] = s*x[2lt+j]
            int gl = 2 * lt + j;
            float v = (gl < Lin) ? xb[(size_t)(ci0 + ci) * inRS + gl] : 0.f;
            xs[ci][j] = v * sb[ci0 + ci];
        }
        for (int idx = t; idx < 32 * 192; idx += 256) {
            int ci = idx / 192, rem = idx % 192;
            int k = rem >> 6, co = rem & 63;
            ws[ci][k][co] = w[((size_t)(cot + co) * CIN + ci0 + ci) * 3 + k];
        }
        __syncthreads();
        for (int ci = 0; ci < 32; ++ci) {
            float xv[10];
            #pragma unroll
            for (int i = 0; i < 10; ++i) xv[i] = xs[ci][lq * 8 + i];
            #pragma unroll
            for (int k = 0; k < 3; ++k)
                #pragma unroll
                for (int cc = 0; cc < 4; ++cc) {
                    float wv = ws[ci][k][cq * 4 + cc];
                    #pragma unroll
                    for (int jj = 0; jj < 4; ++jj)
                        acc[cc][jj] += wv * xv[2 * jj + k];
                }
        }
    }
    float* ob = outp + (size_t)b * COUT * outRS;
    #pragma unroll
    for (int cc = 0; cc < 4; ++cc) {
        int co = cot + cq * 4 + cc;
        float dm = demod[b * COUT + co] * KSCALE;
        float bi = bias[co];
        #pragma unroll
        for (int jj = 0; jj < 4; ++jj)
            ob[(size_t)co * outRS + lt + lq * 4 + jj] = acc[cc][jj] * dm + bi;
    }
}

// ---------------- 4-tap FIR blur with zero padding ----------------
__global__ __launch_bounds__(256) void blur_k(
    const float* __restrict__ in, int Lin, int inRS,
    float* __restrict__ outp, int Lout, int outRS,
    int pad, float c0, float c1, float c2, float c3)
{
    int row = blockIdx.y;   // group-local (b*256 + c)
    int j = blockIdx.x * 256 + threadIdx.x;
    if (j >= Lout) return;
    const float* rp = in + (size_t)row * inRS;
    int base = j - pad;
    float acc = 0.f;
    int i0 = base + 0; if (i0 >= 0 && i0 < Lin) acc += c0 * rp[i0];
    int i1 = base + 1; if (i1 >= 0 && i1 < Lin) acc += c1 * rp[i1];
    int i2 = base + 2; if (i2 >= 0 && i2 < Lin) acc += c2 * rp[i2];
    int i3 = base + 3; if (i3 >= 0 && i3 < Lin) acc += c3 * rp[i3];
    outp[(size_t)row * outRS + j] = acc;
}

extern "C" void kernel_launch(void* const* d_in, const int* in_sizes, int n_in,
                              void* d_out, int out_size, void* d_ws, size_t ws_size,
                              hipStream_t stream) {
    const float* x       = (const float*)d_in[0];
    const float* style   = (const float*)d_in[1];
    const float* weights = (const float*)d_in[2];
    const float* biases  = (const float*)d_in[3];
    const float* mod_w   = (const float*)d_in[4];
    const float* mod_b   = (const float*)d_in[5];
    float* out = (float*)d_out;

    float* s_all = (float*)d_ws;                 // 4*16*256
    float* demod_all = s_all + 4 * NB * CIN;     // 4*16*256
    float* bufBase = demod_all + 4 * NB * CIN;

    const size_t WL = (size_t)COUT * CIN * 3;    // per-layer weight elems
    const int SL = NB * CIN;                     // per-layer s/demod elems

    // adaptive batch grouping so ping-pong buffers fit ws_size
    const size_t fixedF = (size_t)8 * NB * CIN;
    const size_t perSampleF = (size_t)2 * CIN * 8208;
    size_t availF = ws_size / sizeof(float);
    int g = 1;
    if (availF > fixedF) {
        size_t gg = (availF - fixedF) / perSampleF;
        if (gg < 1) gg = 1;
        if (gg > NB) gg = NB;
        g = (int)gg;
    }
    const size_t bufElems = (size_t)g * CIN * 8208;
    float* bufA = bufBase;
    float* bufB = bufBase + bufElems;

    mod_k<<<64, 256, 0, stream>>>(style, weights, mod_w, mod_b, s_all, demod_all);

    for (int b0 = 0; b0 < NB; b0 += g) {
        int gb = NB - b0 < g ? NB - b0 : g;

        // layer 0: same, L=4096: x -> bufA (stride 4096)
        conv_same_k<<<dim3(64, 4, gb), 256, 0, stream>>>(
            x + (size_t)b0 * CIN * 4096, 4096, 4096,
            weights + 0 * WL, s_all + 0 * SL + b0 * CIN, demod_all + 0 * SL + b0 * CIN,
            biases + 0 * COUT, bufA, 4096);

        // layer 1: upsample: bufA -> bufB (len 8193, stride 8208), bias pre-blur
        upconv_k<<<dim3(129, 4, gb), 256, 0, stream>>>(
            bufA, 4096, 4096,
            weights + 1 * WL, s_all + 1 * SL + b0 * CIN, demod_all + 1 * SL + b0 * CIN,
            biases + 1 * COUT, bufB, 8208, 8193);
        // blur 2*bk, pad(1,1): bufB -> bufA (len 8192, stride 8192)
        blur_k<<<dim3(32, gb * CIN), 256, 0, stream>>>(
            bufB, 8193, 8208, bufA, 8192, 8192, 1, 0.25f, 0.75f, 0.75f, 0.25f);

        // layer 2: same, L=8192: bufA -> bufB (stride 8192)
        conv_same_k<<<dim3(128, 4, gb), 256, 0, stream>>>(
            bufA, 8192, 8192,
            weights + 2 * WL, s_all + 2 * SL + b0 * CIN, demod_all + 2 * SL + b0 * CIN,
            biases + 2 * COUT, bufB, 8192);

        // layer 3: blur bk, pad(2,2): bufB -> bufA (len 8193, stride 8208)
        blur_k<<<dim3(33, gb * CIN), 256, 0, stream>>>(
            bufB, 8192, 8192, bufA, 8193, 8208, 2, 0.125f, 0.375f, 0.375f, 0.125f);
        // stride-2 conv: bufA -> out (len 4096)
        conv_down_k<<<dim3(64, 4, gb), 256, 0, stream>>>(
            bufA, 8193, 8208,
            weights + 3 * WL, s_all + 3 * SL + b0 * CIN, demod_all + 3 * SL + b0 * CIN,
            biases + 3 * COUT, out + (size_t)b0 * COUT * 4096, 4096);
    }
}

// Round 5
// 1961.476 us; speedup vs baseline: 1.7374x; 1.7374x over previous
//
#include <hip/hip_runtime.h>
#include <math.h>

#define CIN 256
#define COUT 256
#define SD 512
#define NB 16
#define KSCALE (1.0f / 48.0f)   // 1/sqrt(256*9)
#define MEPS 1e-8f

typedef __attribute__((ext_vector_type(8))) short short8;
typedef __attribute__((ext_vector_type(4))) float floatx4;

__device__ inline unsigned short f2bf(float f) {
    union { float f; unsigned int u; } v; v.f = f;
    unsigned int u = v.u;
    return (unsigned short)((u + 0x7FFFu + ((u >> 16) & 1u)) >> 16);
}

// ---------------- modulation: s and demod for all 4 layers (unchanged, verified) ------
__global__ __launch_bounds__(256) void mod_k(
    const float* __restrict__ style, const float* __restrict__ weights,
    const float* __restrict__ mod_w, const float* __restrict__ mod_b,
    float* __restrict__ s_all, float* __restrict__ demod_all)
{
    int layer = blockIdx.x >> 4;
    int b = blockIdx.x & 15;
    int t = threadIdx.x;
    __shared__ float st[SD];
    __shared__ float s2[CIN];

    for (int j = t; j < SD; j += 256) st[j] = style[b * SD + j];
    __syncthreads();

    const float* mw = mod_w + ((size_t)layer * CIN + t) * SD;
    float acc = 0.f;
    for (int j = 0; j < SD; ++j) acc += mw[j] * st[j];
    float s = acc + mod_b[layer * CIN + t];
    s_all[((size_t)layer * NB + b) * CIN + t] = s;
    s2[t] = s * s;
    __syncthreads();

    const float* wr = weights + ((size_t)layer * COUT + t) * (CIN * 3);
    float d = 0.f;
    for (int ci = 0; ci < CIN; ++ci) {
        float w0 = wr[ci * 3 + 0], w1 = wr[ci * 3 + 1], w2 = wr[ci * 3 + 2];
        d += (w0 * w0 + w1 * w1 + w2 * w2) * s2[ci];
    }
    demod_all[((size_t)layer * NB + b) * CIN + t] = rsqrtf(KSCALE * KSCALE * d + MEPS);
}

// ============ MFMA same-conv: 64co x 128l per block, 4 waves (2co x 2l) ============
// out[co,l] = dm[co]*KSCALE * sum_{ci,k} w[co,ci,k] * s[ci] * x[ci, l+k-1] + bias[co]
__global__ __launch_bounds__(256) void conv_same_mfma(
    const float* __restrict__ in, int L, int inRS,
    const float* __restrict__ w, const float* __restrict__ s,
    const float* __restrict__ demod, const float* __restrict__ bias,
    float* __restrict__ outp, int outRS)
{
    __shared__ __align__(16) unsigned short Xt[130 * 72];   // [row=l0-1+r][ci]
    __shared__ __align__(16) unsigned short Wt[3 * 64 * 72]; // [k][co][ci]
    int l0 = blockIdx.x * 128;
    int cot = blockIdx.y * 64;
    int b = blockIdx.z;
    int t = threadIdx.x;
    int lane = t & 63, wv = t >> 6;
    int wm = wv >> 1, wn = wv & 1;
    int lr = lane & 15, lg = lane >> 4;

    const float* xb = in + (size_t)b * CIN * inRS;
    const float* sb = s + b * CIN;

    floatx4 acc[2][4];
    #pragma unroll
    for (int i = 0; i < 2; ++i)
        #pragma unroll
        for (int j = 0; j < 4; ++j) acc[i][j] = (floatx4)0.f;

    for (int ci0 = 0; ci0 < CIN; ci0 += 64) {
        __syncthreads();
        for (int idx = t; idx < 64 * 130; idx += 256) {
            int ci = idx / 130, r = idx % 130;
            int gl = l0 - 1 + r;
            float v = (gl >= 0 && gl < L) ? xb[(size_t)(ci0 + ci) * inRS + gl] : 0.f;
            Xt[r * 72 + ci] = f2bf(v * sb[ci0 + ci]);
        }
        for (int idx = t; idx < 64 * 192; idx += 256) {
            int co = idx / 192, rem = idx % 192;
            int ci = rem / 3, k = rem % 3;
            Wt[k * 4608 + co * 72 + ci] =
                f2bf(w[(size_t)(cot + co) * 768 + (size_t)(ci0 + ci) * 3 + k]);
        }
        __syncthreads();
        #pragma unroll
        for (int k3 = 0; k3 < 3; ++k3)
            #pragma unroll
            for (int kk = 0; kk < 2; ++kk) {
                short8 a0 = *(const short8*)&Wt[k3 * 4608 + (wm * 32 + lr) * 72 + kk * 32 + lg * 8];
                short8 a1 = *(const short8*)&Wt[k3 * 4608 + (wm * 32 + 16 + lr) * 72 + kk * 32 + lg * 8];
                #pragma unroll
                for (int nn = 0; nn < 4; ++nn) {
                    short8 bq = *(const short8*)&Xt[(wn * 64 + nn * 16 + lr + k3) * 72 + kk * 32 + lg * 8];
                    acc[0][nn] = __builtin_amdgcn_mfma_f32_16x16x32_bf16(a0, bq, acc[0][nn], 0, 0, 0);
                    acc[1][nn] = __builtin_amdgcn_mfma_f32_16x16x32_bf16(a1, bq, acc[1][nn], 0, 0, 0);
                }
            }
    }
    float* ob = outp + (size_t)b * COUT * outRS;
    #pragma unroll
    for (int mm = 0; mm < 2; ++mm)
        #pragma unroll
        for (int nn = 0; nn < 4; ++nn)
            #pragma unroll
            for (int rg = 0; rg < 4; ++rg) {
                int co = cot + wm * 32 + mm * 16 + lg * 4 + rg;
                int l = l0 + wn * 64 + nn * 16 + lr;
                float dm = demod[b * COUT + co] * KSCALE;
                ob[(size_t)co * outRS + l] = acc[mm][nn][rg] * dm + bias[co];
            }
}

// ============ MFMA stride-2 down-conv: 64co x 64lout per block ============
// out[co,l] = dm[co]*KSCALE * sum_{ci,k} w[co,ci,k] * s[ci] * xb[ci, 2l+k] + bias[co]
__global__ __launch_bounds__(256) void conv_down_mfma(
    const float* __restrict__ in, int Lin, int inRS,
    const float* __restrict__ w, const float* __restrict__ s,
    const float* __restrict__ demod, const float* __restrict__ bias,
    float* __restrict__ outp, int outRS)
{
    __shared__ __align__(16) unsigned short Xt[130 * 72];   // [row = 2*l0 + r][ci]
    __shared__ __align__(16) unsigned short Wt[3 * 64 * 72];
    int l0 = blockIdx.x * 64;
    int cot = blockIdx.y * 64;
    int b = blockIdx.z;
    int t = threadIdx.x;
    int lane = t & 63, wv = t >> 6;
    int wm = wv >> 1, wn = wv & 1;
    int lr = lane & 15, lg = lane >> 4;

    const float* xb = in + (size_t)b * CIN * inRS;
    const float* sb = s + b * CIN;

    floatx4 acc[2][2];
    #pragma unroll
    for (int i = 0; i < 2; ++i)
        #pragma unroll
        for (int j = 0; j < 2; ++j) acc[i][j] = (floatx4)0.f;

    for (int ci0 = 0; ci0 < CIN; ci0 += 64) {
        __syncthreads();
        for (int idx = t; idx < 64 * 130; idx += 256) {
            int ci = idx / 130, r = idx % 130;
            int gl = 2 * l0 + r;
            float v = (gl < Lin) ? xb[(size_t)(ci0 + ci) * inRS + gl] : 0.f;
            Xt[r * 72 + ci] = f2bf(v * sb[ci0 + ci]);
        }
        for (int idx = t; idx < 64 * 192; idx += 256) {
            int co = idx / 192, rem = idx % 192;
            int ci = rem / 3, k = rem % 3;
            Wt[k * 4608 + co * 72 + ci] =
                f2bf(w[(size_t)(cot + co) * 768 + (size_t)(ci0 + ci) * 3 + k]);
        }
        __syncthreads();
        #pragma unroll
        for (int k3 = 0; k3 < 3; ++k3)
            #pragma unroll
            for (int kk = 0; kk < 2; ++kk) {
                short8 a0 = *(const short8*)&Wt[k3 * 4608 + (wm * 32 + lr) * 72 + kk * 32 + lg * 8];
                short8 a1 = *(const short8*)&Wt[k3 * 4608 + (wm * 32 + 16 + lr) * 72 + kk * 32 + lg * 8];
                #pragma unroll
                for (int nn = 0; nn < 2; ++nn) {
                    short8 bq = *(const short8*)&Xt[(2 * (wn * 32 + nn * 16 + lr) + k3) * 72 + kk * 32 + lg * 8];
                    acc[0][nn] = __builtin_amdgcn_mfma_f32_16x16x32_bf16(a0, bq, acc[0][nn], 0, 0, 0);
                    acc[1][nn] = __builtin_amdgcn_mfma_f32_16x16x32_bf16(a1, bq, acc[1][nn], 0, 0, 0);
                }
            }
    }
    float* ob = outp + (size_t)b * COUT * outRS;
    #pragma unroll
    for (int mm = 0; mm < 2; ++mm)
        #pragma unroll
        for (int nn = 0; nn < 2; ++nn)
            #pragma unroll
            for (int rg = 0; rg < 4; ++rg) {
                int co = cot + wm * 32 + mm * 16 + lg * 4 + rg;
                int l = l0 + wn * 32 + nn * 16 + lr;
                float dm = demod[b * COUT + co] * KSCALE;
                ob[(size_t)co * outRS + l] = acc[mm][nn][rg] * dm + bias[co];
            }
}

// ============ MFMA transpose-conv stride 2: 64co x 64m per block (128 outputs) ========
// out[o, 2m+0] = s[o]*( sum_c K*dm[c]*w[c,o,0]*x[c,m] + K*dm[c]*w[c,o,2]*x[c,m-1] ) + bias
// out[o, 2m+1] = s[o]*( sum_c K*dm[c]*w[c,o,1]*x[c,m] ) + bias
__global__ __launch_bounds__(256) void upconv_mfma(
    const float* __restrict__ in, int Lin, int inRS,
    const float* __restrict__ w,       // indexed w[c, o, k]
    const float* __restrict__ s,       // output-channel scale
    const float* __restrict__ demod,   // input-channel scale
    const float* __restrict__ bias,
    float* __restrict__ outp, int outRS, int Lout)
{
    __shared__ __align__(16) unsigned short Xt[66 * 72];    // [row = m0-1+r][ci]
    __shared__ __align__(16) unsigned short Wt[3 * 64 * 72]; // [k][o][c]
    int m0 = blockIdx.x * 64;
    int cot = blockIdx.y * 64;
    int b = blockIdx.z;
    int t = threadIdx.x;
    int lane = t & 63, wv = t >> 6;
    int wm = wv >> 1, wn = wv & 1;
    int lr = lane & 15, lg = lane >> 4;

    const float* xb = in + (size_t)b * CIN * inRS;
    const float* db = demod + b * CIN;

    floatx4 accE[2][2], accO[2][2];
    #pragma unroll
    for (int i = 0; i < 2; ++i)
        #pragma unroll
        for (int j = 0; j < 2; ++j) { accE[i][j] = (floatx4)0.f; accO[i][j] = (floatx4)0.f; }

    for (int ci0 = 0; ci0 < CIN; ci0 += 64) {
        __syncthreads();
        for (int idx = t; idx < 64 * 65; idx += 256) {
            int ci = idx / 65, r = idx % 65;
            int gl = m0 - 1 + r;
            float v = (gl >= 0 && gl < Lin) ? xb[(size_t)(ci0 + ci) * inRS + gl] : 0.f;
            Xt[r * 72 + ci] = f2bf(v * db[ci0 + ci] * KSCALE);
        }
        for (int idx = t; idx < 64 * 192; idx += 256) {
            int ci = idx / 192, rem = idx % 192;
            int co = rem / 3, k = rem % 3;
            Wt[k * 4608 + co * 72 + ci] =
                f2bf(w[(size_t)(ci0 + ci) * 768 + (size_t)(cot + co) * 3 + k]);
        }
        __syncthreads();
        #pragma unroll
        for (int kk = 0; kk < 2; ++kk) {
            short8 w0a = *(const short8*)&Wt[0 * 4608 + (wm * 32 + lr) * 72 + kk * 32 + lg * 8];
            short8 w0b = *(const short8*)&Wt[0 * 4608 + (wm * 32 + 16 + lr) * 72 + kk * 32 + lg * 8];
            short8 w1a = *(const short8*)&Wt[1 * 4608 + (wm * 32 + lr) * 72 + kk * 32 + lg * 8];
            short8 w1b = *(const short8*)&Wt[1 * 4608 + (wm * 32 + 16 + lr) * 72 + kk * 32 + lg * 8];
            short8 w2a = *(const short8*)&Wt[2 * 4608 + (wm * 32 + lr) * 72 + kk * 32 + lg * 8];
            short8 w2b = *(const short8*)&Wt[2 * 4608 + (wm * 32 + 16 + lr) * 72 + kk * 32 + lg * 8];
            #pragma unroll
            for (int nn = 0; nn < 2; ++nn) {
                int mrow = wn * 32 + nn * 16 + lr;
                short8 xm = *(const short8*)&Xt[mrow * 72 + kk * 32 + lg * 8];        // x[m-1]
                short8 xc = *(const short8*)&Xt[(mrow + 1) * 72 + kk * 32 + lg * 8];  // x[m]
                accE[0][nn] = __builtin_amdgcn_mfma_f32_16x16x32_bf16(w0a, xc, accE[0][nn], 0, 0, 0);
                accE[0][nn] = __builtin_amdgcn_mfma_f32_16x16x32_bf16(w2a, xm, accE[0][nn], 0, 0, 0);
                accO[0][nn] = __builtin_amdgcn_mfma_f32_16x16x32_bf16(w1a, xc, accO[0][nn], 0, 0, 0);
                accE[1][nn] = __builtin_amdgcn_mfma_f32_16x16x32_bf16(w0b, xc, accE[1][nn], 0, 0, 0);
                accE[1][nn] = __builtin_amdgcn_mfma_f32_16x16x32_bf16(w2b, xm, accE[1][nn], 0, 0, 0);
                accO[1][nn] = __builtin_amdgcn_mfma_f32_16x16x32_bf16(w1b, xc, accO[1][nn], 0, 0, 0);
            }
        }
    }
    float* ob = outp + (size_t)b * COUT * outRS;
    #pragma unroll
    for (int mm = 0; mm < 2; ++mm)
        #pragma unroll
        for (int nn = 0; nn < 2; ++nn)
            #pragma unroll
            for (int rg = 0; rg < 4; ++rg) {
                int co = cot + wm * 32 + mm * 16 + lg * 4 + rg;
                int m = m0 + wn * 32 + nn * 16 + lr;
                float os = s[b * COUT + co];
                float bi = bias[co];
                int nE = 2 * m;
                if (nE < Lout) ob[(size_t)co * outRS + nE] = accE[mm][nn][rg] * os + bi;
                int nO = 2 * m + 1;
                if (nO < Lout) ob[(size_t)co * outRS + nO] = accO[mm][nn][rg] * os + bi;
            }
}

// ---------------- 4-tap FIR blur with zero padding (unchanged) ----------------
__global__ __launch_bounds__(256) void blur_k(
    const float* __restrict__ in, int Lin, int inRS,
    float* __restrict__ outp, int Lout, int outRS,
    int pad, float c0, float c1, float c2, float c3)
{
    int row = blockIdx.y;
    int j = blockIdx.x * 256 + threadIdx.x;
    if (j >= Lout) return;
    const float* rp = in + (size_t)row * inRS;
    int base = j - pad;
    float acc = 0.f;
    int i0 = base + 0; if (i0 >= 0 && i0 < Lin) acc += c0 * rp[i0];
    int i1 = base + 1; if (i1 >= 0 && i1 < Lin) acc += c1 * rp[i1];
    int i2 = base + 2; if (i2 >= 0 && i2 < Lin) acc += c2 * rp[i2];
    int i3 = base + 3; if (i3 >= 0 && i3 < Lin) acc += c3 * rp[i3];
    outp[(size_t)row * outRS + j] = acc;
}

extern "C" void kernel_launch(void* const* d_in, const int* in_sizes, int n_in,
                              void* d_out, int out_size, void* d_ws, size_t ws_size,
                              hipStream_t stream) {
    const float* x       = (const float*)d_in[0];
    const float* style   = (const float*)d_in[1];
    const float* weights = (const float*)d_in[2];
    const float* biases  = (const float*)d_in[3];
    const float* mod_w   = (const float*)d_in[4];
    const float* mod_b   = (const float*)d_in[5];
    float* out = (float*)d_out;

    float* s_all = (float*)d_ws;
    float* demod_all = s_all + 4 * NB * CIN;
    float* bufBase = demod_all + 4 * NB * CIN;

    const size_t WL = (size_t)COUT * CIN * 3;
    const int SL = NB * CIN;

    const size_t fixedF = (size_t)8 * NB * CIN;
    const size_t perSampleF = (size_t)2 * CIN * 8208;
    size_t availF = ws_size / sizeof(float);
    int g = 1;
    if (availF > fixedF) {
        size_t gg = (availF - fixedF) / perSampleF;
        if (gg < 1) gg = 1;
        if (gg > NB) gg = NB;
        g = (int)gg;
    }
    const size_t bufElems = (size_t)g * CIN * 8208;
    float* bufA = bufBase;
    float* bufB = bufBase + bufElems;

    mod_k<<<64, 256, 0, stream>>>(style, weights, mod_w, mod_b, s_all, demod_all);

    for (int b0 = 0; b0 < NB; b0 += g) {
        int gb = NB - b0 < g ? NB - b0 : g;

        // layer 0: same, L=4096: x -> bufA (stride 4096)
        conv_same_mfma<<<dim3(32, 4, gb), 256, 0, stream>>>(
            x + (size_t)b0 * CIN * 4096, 4096, 4096,
            weights + 0 * WL, s_all + 0 * SL + b0 * CIN, demod_all + 0 * SL + b0 * CIN,
            biases + 0 * COUT, bufA, 4096);

        // layer 1: upsample: bufA -> bufB (len 8193, stride 8208)
        upconv_mfma<<<dim3(65, 4, gb), 256, 0, stream>>>(
            bufA, 4096, 4096,
            weights + 1 * WL, s_all + 1 * SL + b0 * CIN, demod_all + 1 * SL + b0 * CIN,
            biases + 1 * COUT, bufB, 8208, 8193);
        // blur 2*bk, pad(1,1): bufB -> bufA (len 8192, stride 8192)
        blur_k<<<dim3(32, gb * CIN), 256, 0, stream>>>(
            bufB, 8193, 8208, bufA, 8192, 8192, 1, 0.25f, 0.75f, 0.75f, 0.25f);

        // layer 2: same, L=8192: bufA -> bufB (stride 8192)
        conv_same_mfma<<<dim3(64, 4, gb), 256, 0, stream>>>(
            bufA, 8192, 8192,
            weights + 2 * WL, s_all + 2 * SL + b0 * CIN, demod_all + 2 * SL + b0 * CIN,
            biases + 2 * COUT, bufB, 8192);

        // layer 3: blur bk, pad(2,2): bufB -> bufA (len 8193, stride 8208)
        blur_k<<<dim3(33, gb * CIN), 256, 0, stream>>>(
            bufB, 8192, 8192, bufA, 8193, 8208, 2, 0.125f, 0.375f, 0.375f, 0.125f);
        // stride-2 conv: bufA -> out (len 4096)
        conv_down_mfma<<<dim3(64, 4, gb), 256, 0, stream>>>(
            bufA, 8193, 8208,
            weights + 3 * WL, s_all + 3 * SL + b0 * CIN, demod_all + 3 * SL + b0 * CIN,
            biases + 3 * COUT, out + (size_t)b0 * COUT * 4096, 4096);
    }
}

// Round 7
// 801.938 us; speedup vs baseline: 4.2495x; 2.4459x over previous
//
#include <hip/hip_runtime.h>
#include <math.h>
#include <stddef.h>

#define CIN 256
#define COUT 256
#define SD 512
#define NB 16
#define KSCALE (1.0f / 48.0f)   // 1/sqrt(256*9)
#define MEPS 1e-8f
#define SRROW 8320               // per-sample row stride (rows of 256 bf16)

typedef __attribute__((ext_vector_type(8))) short short8;
typedef __attribute__((ext_vector_type(4))) float floatx4;
typedef unsigned short ushort;

__device__ inline ushort f2bf(float f) {
    union { float f; unsigned int u; } v; v.f = f;
    unsigned int u = v.u;
    return (ushort)((u + 0x7FFFu + ((u >> 16) & 1u)) >> 16);
}
__device__ inline float bf2f(ushort h) {
    union { unsigned int u; float f; } v; v.u = ((unsigned int)h) << 16;
    return v.f;
}

// ---------------- modulation (verified round 4/5) ----------------
__global__ __launch_bounds__(256) void mod_k(
    const float* __restrict__ style, const float* __restrict__ weights,
    const float* __restrict__ mod_w, const float* __restrict__ mod_b,
    float* __restrict__ s_all, float* __restrict__ demod_all)
{
    int layer = blockIdx.x >> 4;
    int b = blockIdx.x & 15;
    int t = threadIdx.x;
    __shared__ float st[SD];
    __shared__ float s2[CIN];

    for (int j = t; j < SD; j += 256) st[j] = style[b * SD + j];
    __syncthreads();

    const float* mw = mod_w + ((size_t)layer * CIN + t) * SD;
    float acc = 0.f;
    for (int j = 0; j < SD; ++j) acc += mw[j] * st[j];
    float s = acc + mod_b[layer * CIN + t];
    s_all[((size_t)layer * NB + b) * CIN + t] = s;
    s2[t] = s * s;
    __syncthreads();

    const float* wr = weights + ((size_t)layer * COUT + t) * (CIN * 3);
    float d = 0.f;
    for (int ci = 0; ci < CIN; ++ci) {
        float w0 = wr[ci * 3 + 0], w1 = wr[ci * 3 + 1], w2 = wr[ci * 3 + 2];
        d += (w0 * w0 + w1 * w1 + w2 * w2) * s2[ci];
    }
    demod_all[((size_t)layer * NB + b) * CIN + t] = rsqrtf(KSCALE * KSCALE * d + MEPS);
}

// ---------------- weight prep: bf16, GEMM-friendly layouts ----------------
// layers 0,2,3: Wbf[L][co][tap*256+ci];  layer 1: Wbf[1][tap][o][c]
__global__ __launch_bounds__(256) void wprep_k(
    const float* __restrict__ weights, ushort* __restrict__ Wbf)
{
    int layer = blockIdx.y;
    int idx = blockIdx.x * 256 + threadIdx.x;   // 0..65535
    int a = idx >> 8, c = idx & 255;
    ushort* wl = Wbf + (size_t)layer * 196608;
    if (layer == 1) {
        // a = o, c = contracted c ; read w[c][o][k]
        const float* src = weights + ((size_t)1 * 196608) + ((size_t)c * 256 + a) * 3;
        #pragma unroll
        for (int k = 0; k < 3; ++k)
            wl[(size_t)k * 65536 + a * 256 + c] = f2bf(src[k]);
    } else {
        // a = co, c = ci ; read w[co][ci][k]
        const float* src = weights + ((size_t)layer * 196608) + ((size_t)a * 256 + c) * 3;
        #pragma unroll
        for (int k = 0; k < 3; ++k)
            wl[(size_t)a * 768 + k * 256 + c] = f2bf(src[k]);
    }
}

// ---------------- x prep: f32 [ci][l] -> bf16 [l][ci] scaled by s0 ----------------
__global__ __launch_bounds__(256) void xprep_k(
    const float* __restrict__ x, const float* __restrict__ s0,
    ushort* __restrict__ Tout)   // data-row0 base (guard row -1 exists)
{
    __shared__ ushort lt[64 * 72];
    int l0 = blockIdx.x * 64, ci0 = blockIdx.y * 64;
    int b = blockIdx.z;
    int t = threadIdx.x;
    const float* xb = x + (size_t)b * CIN * 4096;
    const float* sb = s0 + b * CIN;

    for (int idx = t; idx < 64 * 64; idx += 256) {
        int ci = idx >> 6, lc = idx & 63;
        float v = xb[(size_t)(ci0 + ci) * 4096 + l0 + lc] * sb[ci0 + ci];
        lt[lc * 72 + ci] = f2bf(v);
    }
    __syncthreads();
    ushort* ob = Tout + (size_t)b * SRROW * 256;
    for (int idx = t; idx < 64 * 8; idx += 256) {
        int lc = idx >> 3, ch = idx & 7;
        short8 v = *(const short8*)&lt[lc * 72 + ch * 8];
        *(short8*)&ob[(size_t)(l0 + lc) * 256 + ci0 + ch * 8] = v;
    }
}

// ---------------- zero two guard rows per sample (UNDERLYING row coords) ----------------
__global__ __launch_bounds__(256) void guard_k(
    ushort* __restrict__ T, int rowA, int rowB)
{
    int b = blockIdx.x;
    ushort* base = T + (size_t)b * SRROW * 256;
    base[(size_t)rowA * 256 + threadIdx.x] = 0;
    base[(size_t)rowB * 256 + threadIdx.x] = 0;
}

// ================= conv same: block 64co x 128l, K=768 flat =================
// out[l][co] = bf16( (acc*dm[co]*KSCALE + bias[co]) * (post?post[co]*KSCALE:1) )
__global__ __launch_bounds__(256) void conv_same_mfma(
    const ushort* __restrict__ Tin, int L,
    const ushort* __restrict__ Wl,      // [co][768]
    const float* __restrict__ dm, const float* __restrict__ post,
    const float* __restrict__ bias,
    ushort* __restrict__ Tout)
{
    __shared__ __align__(16) ushort Xs[130 * 256];   // 66.5 KB, swizzled
    int l0 = blockIdx.x * 128;
    int cot = blockIdx.y * 64;
    int b = blockIdx.z;
    int t = threadIdx.x;
    int lane = t & 63, wv = t >> 6;
    int lr = lane & 15, lg = lane >> 4;

    const ushort* Tb = Tin + (size_t)b * SRROW * 256;

    for (int idx = t; idx < 130 * 32; idx += 256) {
        int row = idx >> 5, ch = idx & 31;
        const ushort* src = Tb + (ptrdiff_t)(l0 - 1 + row) * 256 + ch * 8;
        short8 v = *(const short8*)src;
        *(short8*)&Xs[row * 256 + ((ch * 8) ^ ((row & 7) * 8))] = v;
    }
    __syncthreads();

    floatx4 acc[4][2];
    #pragma unroll
    for (int i = 0; i < 4; ++i) { acc[i][0] = (floatx4)0.f; acc[i][1] = (floatx4)0.f; }

    #pragma unroll
    for (int tap = 0; tap < 3; ++tap)
        #pragma unroll
        for (int kk = 0; kk < 8; ++kk) {
            short8 a[4];
            #pragma unroll
            for (int mf = 0; mf < 4; ++mf)
                a[mf] = *(const short8*)&Wl[(size_t)(cot + mf * 16 + lr) * 768 + tap * 256 + kk * 32 + lg * 8];
            short8 bf[2];
            #pragma unroll
            for (int nf = 0; nf < 2; ++nf) {
                int row = wv * 32 + nf * 16 + lr + tap;
                int ci = kk * 32 + lg * 8;
                bf[nf] = *(const short8*)&Xs[row * 256 + (ci ^ ((row & 7) * 8))];
            }
            #pragma unroll
            for (int mf = 0; mf < 4; ++mf)
                #pragma unroll
                for (int nf = 0; nf < 2; ++nf)
                    acc[mf][nf] = __builtin_amdgcn_mfma_f32_16x16x32_bf16(a[mf], bf[nf], acc[mf][nf], 0, 0, 0);
        }

    // epilogue: LDS transpose to [l][co] rows, then coalesced bf16 stores
    __syncthreads();
    ushort* Ot = Xs;  // reuse (128 x 72)
    #pragma unroll
    for (int mf = 0; mf < 4; ++mf)
        #pragma unroll
        for (int nf = 0; nf < 2; ++nf)
            #pragma unroll
            for (int rg = 0; rg < 4; ++rg) {
                int lo = wv * 32 + nf * 16 + lr;
                int co = mf * 16 + lg * 4 + rg;
                float dmv = dm[b * COUT + cot + co] * KSCALE;
                float v = acc[mf][nf][rg] * dmv + bias[cot + co];
                if (post) v *= post[b * COUT + cot + co] * KSCALE;
                Ot[lo * 72 + co] = f2bf(v);
            }
    __syncthreads();
    ushort* ob = Tout + (size_t)b * SRROW * 256;
    for (int idx = t; idx < 128 * 8; idx += 256) {
        int lo = idx >> 3, ch = idx & 7;
        short8 v = *(const short8*)&Ot[lo * 72 + ch * 8];
        *(short8*)&ob[(size_t)(l0 + lo) * 256 + cot + ch * 8] = v;
    }
}

// ================= transpose conv stride 2: block 64o x 128m (256 n) =================
// accE(n=2m) = W0*x[m] + W2*x[m-1]; accO(n=2m+1) = W1*x[m]; out = acc*s[o] + bias
__global__ __launch_bounds__(256) void upconv_mfma(
    const ushort* __restrict__ Tin, int Lout,
    const ushort* __restrict__ Wl,      // [tap][o][c]
    const float* __restrict__ s, const float* __restrict__ bias,
    ushort* __restrict__ Tout)
{
    __shared__ __align__(16) ushort Xs[130 * 256];
    int m0 = blockIdx.x * 128;
    int ot = blockIdx.y * 64;
    int b = blockIdx.z;
    int t = threadIdx.x;
    int lane = t & 63, wv = t >> 6;
    int lr = lane & 15, lg = lane >> 4;

    const ushort* Tb = Tin + (size_t)b * SRROW * 256;

    for (int idx = t; idx < 130 * 32; idx += 256) {
        int row = idx >> 5, ch = idx & 31;
        const ushort* src = Tb + (ptrdiff_t)(m0 - 1 + row) * 256 + ch * 8;
        short8 v = *(const short8*)src;
        *(short8*)&Xs[row * 256 + ((ch * 8) ^ ((row & 7) * 8))] = v;
    }
    __syncthreads();

    floatx4 aE[4][2], aO[4][2];
    #pragma unroll
    for (int i = 0; i < 4; ++i)
        #pragma unroll
        for (int j = 0; j < 2; ++j) { aE[i][j] = (floatx4)0.f; aO[i][j] = (floatx4)0.f; }

    #pragma unroll
    for (int kk = 0; kk < 8; ++kk) {
        short8 bm1[2], bm[2];
        #pragma unroll
        for (int nf = 0; nf < 2; ++nf) {
            int r0 = wv * 32 + nf * 16 + lr;       // row r0 = x[m-1], r0+1 = x[m]
            int ci = kk * 32 + lg * 8;
            bm1[nf] = *(const short8*)&Xs[r0 * 256 + (ci ^ ((r0 & 7) * 8))];
            int r1 = r0 + 1;
            bm[nf]  = *(const short8*)&Xs[r1 * 256 + (ci ^ ((r1 & 7) * 8))];
        }
        #pragma unroll
        for (int tap = 0; tap < 3; ++tap) {
            short8 a[4];
            #pragma unroll
            for (int mf = 0; mf < 4; ++mf)
                a[mf] = *(const short8*)&Wl[(size_t)tap * 65536 + (size_t)(ot + mf * 16 + lr) * 256 + kk * 32 + lg * 8];
            #pragma unroll
            for (int mf = 0; mf < 4; ++mf)
                #pragma unroll
                for (int nf = 0; nf < 2; ++nf) {
                    if (tap == 0) aE[mf][nf] = __builtin_amdgcn_mfma_f32_16x16x32_bf16(a[mf], bm[nf],  aE[mf][nf], 0, 0, 0);
                    if (tap == 2) aE[mf][nf] = __builtin_amdgcn_mfma_f32_16x16x32_bf16(a[mf], bm1[nf], aE[mf][nf], 0, 0, 0);
                    if (tap == 1) aO[mf][nf] = __builtin_amdgcn_mfma_f32_16x16x32_bf16(a[mf], bm[nf],  aO[mf][nf], 0, 0, 0);
                }
        }
    }

    __syncthreads();
    ushort* Ot = Xs;   // 256 x 72
    #pragma unroll
    for (int mf = 0; mf < 4; ++mf)
        #pragma unroll
        for (int nf = 0; nf < 2; ++nf)
            #pragma unroll
            for (int rg = 0; rg < 4; ++rg) {
                int mloc = wv * 32 + nf * 16 + lr;
                int co = mf * 16 + lg * 4 + rg;
                float sv = s[b * COUT + ot + co];
                float bi = bias[ot + co];
                Ot[(2 * mloc) * 72 + co]     = f2bf(aE[mf][nf][rg] * sv + bi);
                Ot[(2 * mloc + 1) * 72 + co] = f2bf(aO[mf][nf][rg] * sv + bi);
            }
    __syncthreads();
    ushort* ob = Tout + (size_t)b * SRROW * 256;
    for (int idx = t; idx < 256 * 8; idx += 256) {
        int lo = idx >> 3, ch = idx & 7;
        int n = 2 * m0 + lo;
        if (n < Lout) {
            short8 v = *(const short8*)&Ot[lo * 72 + ch * 8];
            *(short8*)&ob[(size_t)n * 256 + ot + ch * 8] = v;
        }
    }
}

// ================= stride-2 conv: block 128co x 64l -> f32 out [co][l] =================
__global__ __launch_bounds__(256) void conv_down_mfma(
    const ushort* __restrict__ Tin,
    const ushort* __restrict__ Wl,      // [co][768]
    const float* __restrict__ dm, const float* __restrict__ bias,
    float* __restrict__ outp)
{
    __shared__ __align__(16) ushort Xs[130 * 256];
    int l0 = blockIdx.x * 64;
    int cot = blockIdx.y * 128;
    int b = blockIdx.z;
    int t = threadIdx.x;
    int lane = t & 63, wv = t >> 6;
    int wm = wv >> 1, wn = wv & 1;
    int lr = lane & 15, lg = lane >> 4;

    const ushort* Tb = Tin + (size_t)b * SRROW * 256;

    for (int idx = t; idx < 130 * 32; idx += 256) {
        int row = idx >> 5, ch = idx & 31;
        short8 v = *(const short8*)&Tb[(size_t)(2 * l0 + row) * 256 + ch * 8];
        *(short8*)&Xs[row * 256 + ((ch * 8) ^ ((row & 7) * 8))] = v;
    }
    __syncthreads();

    floatx4 acc[4][2];
    #pragma unroll
    for (int i = 0; i < 4; ++i) { acc[i][0] = (floatx4)0.f; acc[i][1] = (floatx4)0.f; }

    #pragma unroll
    for (int tap = 0; tap < 3; ++tap)
        #pragma unroll
        for (int kk = 0; kk < 8; ++kk) {
            short8 a[4];
            #pragma unroll
            for (int mf = 0; mf < 4; ++mf)
                a[mf] = *(const short8*)&Wl[(size_t)(cot + wm * 64 + mf * 16 + lr) * 768 + tap * 256 + kk * 32 + lg * 8];
            short8 bf[2];
            #pragma unroll
            for (int nf = 0; nf < 2; ++nf) {
                int row = 2 * (wn * 32 + nf * 16 + lr) + tap;
                int ci = kk * 32 + lg * 8;
                bf[nf] = *(const short8*)&Xs[row * 256 + (ci ^ ((row & 7) * 8))];
            }
            #pragma unroll
            for (int mf = 0; mf < 4; ++mf)
                #pragma unroll
                for (int nf = 0; nf < 2; ++nf)
                    acc[mf][nf] = __builtin_amdgcn_mfma_f32_16x16x32_bf16(a[mf], bf[nf], acc[mf][nf], 0, 0, 0);
        }

    float* ob = outp + (size_t)b * COUT * 4096;
    #pragma unroll
    for (int mf = 0; mf < 4; ++mf)
        #pragma unroll
        for (int nf = 0; nf < 2; ++nf)
            #pragma unroll
            for (int rg = 0; rg < 4; ++rg) {
                int co = cot + wm * 64 + mf * 16 + lg * 4 + rg;
                int l = l0 + wn * 32 + nf * 16 + lr;
                float dmv = dm[b * COUT + co] * KSCALE;
                ob[(size_t)co * 4096 + l] = acc[mf][nf][rg] * dmv + bias[co];
            }
}

// ---------------- bf16 blur (channel-last), optional per-ci scale fold ----------------
__global__ __launch_bounds__(256) void blur_bf16_k(
    const ushort* __restrict__ in, int Lin,
    ushort* __restrict__ outp, int Lout,
    const float* __restrict__ scale,   // [b][256] or null
    int pad, float c0, float c1, float c2, float c3)
{
    int b = blockIdx.y;
    int idx = blockIdx.x * 256 + threadIdx.x;
    if (idx >= Lout * 32) return;
    int row = idx >> 5, ci = (idx & 31) * 8;
    const ushort* ib = in + (size_t)b * SRROW * 256;
    float acc[8] = {};
    int base = row - pad;
    float cf[4] = {c0, c1, c2, c3};
    #pragma unroll
    for (int i = 0; i < 4; ++i) {
        int r = base + i;
        if (r >= 0 && r < Lin) {
            short8 v = *(const short8*)&ib[(size_t)r * 256 + ci];
            #pragma unroll
            for (int j = 0; j < 8; ++j) acc[j] += cf[i] * bf2f((ushort)v[j]);
        }
    }
    short8 o;
    #pragma unroll
    for (int j = 0; j < 8; ++j) {
        float sv = scale ? scale[b * CIN + ci + j] : 1.f;
        o[j] = (short)f2bf(acc[j] * sv);
    }
    *(short8*)&outp[((size_t)b * SRROW + row) * 256 + ci] = o;
}

extern "C" void kernel_launch(void* const* d_in, const int* in_sizes, int n_in,
                              void* d_out, int out_size, void* d_ws, size_t ws_size,
                              hipStream_t stream) {
    const float* x       = (const float*)d_in[0];
    const float* style   = (const float*)d_in[1];
    const float* weights = (const float*)d_in[2];
    const float* biases  = (const float*)d_in[3];
    const float* mod_w   = (const float*)d_in[4];
    const float* mod_b   = (const float*)d_in[5];
    float* out = (float*)d_out;

    float* s_all = (float*)d_ws;                       // 4*16*256
    float* demod_all = s_all + 4 * NB * CIN;           // 4*16*256
    const size_t WBF_OFF = 131072;                     // bytes
    const size_t BUF_OFF = WBF_OFF + 1572864;          // + Wbf bytes
    ushort* Wbf = (ushort*)((char*)d_ws + WBF_OFF);
    ushort* bufBase = (ushort*)((char*)d_ws + BUF_OFF);

    const int SL = NB * CIN;
    const size_t perSampleB = (size_t)2 * SRROW * 256 * sizeof(ushort);
    size_t availB = ws_size > BUF_OFF ? ws_size - BUF_OFF : 0;
    int g = (int)(availB / perSampleB);
    if (g < 1) g = 1;
    if (g > NB) g = NB;

    const size_t sElems = (size_t)SRROW * 256;
    ushort* bufAU = bufBase;                           // underlying bases
    ushort* bufBU = bufBase + (size_t)g * sElems;
    ushort* bufA = bufAU + 256;                        // data row 0 (guard at underlying 0)
    ushort* bufB = bufBU + 256;

    mod_k<<<64, 256, 0, stream>>>(style, weights, mod_w, mod_b, s_all, demod_all);
    wprep_k<<<dim3(256, 4), 256, 0, stream>>>(weights, Wbf);

    for (int b0 = 0; b0 < NB; b0 += g) {
        int gb = NB - b0 < g ? NB - b0 : g;

        // T0 = bf16(x * s0) channel-last -> bufA ; guards at data {-1, 4096} = underlying {0, 4097}
        xprep_k<<<dim3(64, 4, gb), 256, 0, stream>>>(
            x + (size_t)b0 * CIN * 4096, s_all + 0 * SL + b0 * CIN, bufA);
        guard_k<<<gb, 256, 0, stream>>>(bufAU, 0, 4097);

        // conv0 (same, L=4096): bufA -> bufB = T1 (post = dm1*KSCALE folded)
        conv_same_mfma<<<dim3(32, 4, gb), 256, 0, stream>>>(
            bufA, 4096, Wbf + 0 * 196608,
            demod_all + 0 * SL + b0 * CIN, demod_all + 1 * SL + b0 * CIN,
            biases + 0 * COUT, bufB);
        guard_k<<<gb, 256, 0, stream>>>(bufBU, 0, 4097);

        // upconv: bufB -> bufA = T2 (8193 data rows, plain bf16)
        upconv_mfma<<<dim3(33, 4, gb), 256, 0, stream>>>(
            bufB, 8193, Wbf + 1 * 196608,
            s_all + 1 * SL + b0 * CIN, biases + 1 * COUT, bufA);

        // blur1 (2*bk, pad 1): T2 -> bufB = T3, fold s2 ; guards at data {-1, 8192}
        blur_bf16_k<<<dim3((8192 * 32 + 255) / 256, gb), 256, 0, stream>>>(
            bufA, 8193, bufB, 8192, s_all + 2 * SL + b0 * CIN,
            1, 0.25f, 0.75f, 0.75f, 0.25f);
        guard_k<<<gb, 256, 0, stream>>>(bufBU, 0, 8193);

        // conv2 (same, L=8192): bufB -> bufA = T4 (no post)
        conv_same_mfma<<<dim3(64, 4, gb), 256, 0, stream>>>(
            bufB, 8192, Wbf + 2 * 196608,
            demod_all + 2 * SL + b0 * CIN, (const float*)nullptr,
            biases + 2 * COUT, bufA);

        // blur2 (bk, pad 2): T4 -> bufB = T5 (8193 data rows), fold s3
        blur_bf16_k<<<dim3((8193 * 32 + 255) / 256, gb), 256, 0, stream>>>(
            bufA, 8192, bufB, 8193, s_all + 3 * SL + b0 * CIN,
            2, 0.125f, 0.375f, 0.375f, 0.125f);
        // tail guard for down-conv staging over-read: data row 8193 = underlying 8194
        guard_k<<<gb, 256, 0, stream>>>(bufBU, 0, 8194);

        // conv3 (down): bufB -> out f32 [b][co][4096]
        conv_down_mfma<<<dim3(64, 2, gb), 256, 0, stream>>>(
            bufB, Wbf + 3 * 196608,
            demod_all + 3 * SL + b0 * CIN, biases + 3 * COUT,
            out + (size_t)b0 * COUT * 4096);
    }
}

// Round 8
// 704.804 us; speedup vs baseline: 4.8352x; 1.1378x over previous
//
#include <hip/hip_runtime.h>
#include <math.h>
#include <stddef.h>

#define CIN 256
#define COUT 256
#define SD 512
#define NB 16
#define KSCALE (1.0f / 48.0f)   // 1/sqrt(256*9)
#define MEPS 1e-8f
#define SRROW 8320               // per-sample row stride (rows of 256 bf16)

typedef __attribute__((ext_vector_type(8))) short short8;
typedef __attribute__((ext_vector_type(4))) float floatx4;
typedef unsigned short ushort;

__device__ inline ushort f2bf(float f) {
    union { float f; unsigned int u; } v; v.f = f;
    unsigned int u = v.u;
    return (ushort)((u + 0x7FFFu + ((u >> 16) & 1u)) >> 16);
}
__device__ inline float bf2f(ushort h) {
    union { unsigned int u; float f; } v; v.u = ((unsigned int)h) << 16;
    return v.f;
}

// ---------------- modulation (verified round 4/5) ----------------
__global__ __launch_bounds__(256) void mod_k(
    const float* __restrict__ style, const float* __restrict__ weights,
    const float* __restrict__ mod_w, const float* __restrict__ mod_b,
    float* __restrict__ s_all, float* __restrict__ demod_all)
{
    int layer = blockIdx.x >> 4;
    int b = blockIdx.x & 15;
    int t = threadIdx.x;
    __shared__ float st[SD];
    __shared__ float s2[CIN];

    for (int j = t; j < SD; j += 256) st[j] = style[b * SD + j];
    __syncthreads();

    const float* mw = mod_w + ((size_t)layer * CIN + t) * SD;
    float acc = 0.f;
    for (int j = 0; j < SD; ++j) acc += mw[j] * st[j];
    float s = acc + mod_b[layer * CIN + t];
    s_all[((size_t)layer * NB + b) * CIN + t] = s;
    s2[t] = s * s;
    __syncthreads();

    const float* wr = weights + ((size_t)layer * COUT + t) * (CIN * 3);
    float d = 0.f;
    for (int ci = 0; ci < CIN; ++ci) {
        float w0 = wr[ci * 3 + 0], w1 = wr[ci * 3 + 1], w2 = wr[ci * 3 + 2];
        d += (w0 * w0 + w1 * w1 + w2 * w2) * s2[ci];
    }
    demod_all[((size_t)layer * NB + b) * CIN + t] = rsqrtf(KSCALE * KSCALE * d + MEPS);
}

// ---------------- weight prep (verified round 7) ----------------
__global__ __launch_bounds__(256) void wprep_k(
    const float* __restrict__ weights, ushort* __restrict__ Wbf)
{
    int layer = blockIdx.y;
    int idx = blockIdx.x * 256 + threadIdx.x;
    int a = idx >> 8, c = idx & 255;
    ushort* wl = Wbf + (size_t)layer * 196608;
    if (layer == 1) {
        const float* src = weights + ((size_t)1 * 196608) + ((size_t)c * 256 + a) * 3;
        #pragma unroll
        for (int k = 0; k < 3; ++k)
            wl[(size_t)k * 65536 + a * 256 + c] = f2bf(src[k]);
    } else {
        const float* src = weights + ((size_t)layer * 196608) + ((size_t)a * 256 + c) * 3;
        #pragma unroll
        for (int k = 0; k < 3; ++k)
            wl[(size_t)a * 768 + k * 256 + c] = f2bf(src[k]);
    }
}

// ---------------- x prep (verified round 7) ----------------
__global__ __launch_bounds__(256) void xprep_k(
    const float* __restrict__ x, const float* __restrict__ s0,
    ushort* __restrict__ Tout)
{
    __shared__ ushort lt[64 * 72];
    int l0 = blockIdx.x * 64, ci0 = blockIdx.y * 64;
    int b = blockIdx.z;
    int t = threadIdx.x;
    const float* xb = x + (size_t)b * CIN * 4096;
    const float* sb = s0 + b * CIN;

    for (int idx = t; idx < 64 * 64; idx += 256) {
        int ci = idx >> 6, lc = idx & 63;
        float v = xb[(size_t)(ci0 + ci) * 4096 + l0 + lc] * sb[ci0 + ci];
        lt[lc * 72 + ci] = f2bf(v);
    }
    __syncthreads();
    ushort* ob = Tout + (size_t)b * SRROW * 256;
    for (int idx = t; idx < 64 * 8; idx += 256) {
        int lc = idx >> 3, ch = idx & 7;
        short8 v = *(const short8*)&lt[lc * 72 + ch * 8];
        *(short8*)&ob[(size_t)(l0 + lc) * 256 + ci0 + ch * 8] = v;
    }
}

// ---------------- zero guard rows (UNDERLYING coords; verified round 7) -----------
__global__ __launch_bounds__(256) void guard_k(
    ushort* __restrict__ T, int rowA, int rowB)
{
    int b = blockIdx.x;
    ushort* base = T + (size_t)b * SRROW * 256;
    base[(size_t)rowA * 256 + threadIdx.x] = 0;
    base[(size_t)rowB * 256 + threadIdx.x] = 0;
}

// ================= conv same: 64co x 128l, K chunked by 64 ci =================
// FIR=true: staged value = scale[ci] * sum_i cf[i]*Tin[gl-pad+i][ci]  (blur fused)
// FIR=false: staged value = Tin[gl][ci] (relies on guard rows at -1 / L)
template<bool FIR>
__global__ __launch_bounds__(256, 4) void conv_same_mfma(
    const ushort* __restrict__ Tin, int L, int LinT,
    const ushort* __restrict__ Wl,      // [co][768]
    const float* __restrict__ dm, const float* __restrict__ post,
    const float* __restrict__ scale, const float* __restrict__ bias,
    ushort* __restrict__ Tout,
    float c0, float c1, float c2, float c3, int pad)
{
    __shared__ __align__(16) ushort Xs[9216];   // chunk 130x64 (8320) / epilogue 128x72
    int l0 = blockIdx.x * 128;
    int cot = blockIdx.y * 64;
    int b = blockIdx.z;
    int t = threadIdx.x;
    int lane = t & 63, wv = t >> 6;
    int lr = lane & 15, lg = lane >> 4;

    const ushort* Tb = Tin + (size_t)b * SRROW * 256;
    float cf[4] = {c0, c1, c2, c3};

    floatx4 acc[4][2];
    #pragma unroll
    for (int i = 0; i < 4; ++i) { acc[i][0] = (floatx4)0.f; acc[i][1] = (floatx4)0.f; }

    for (int ci0 = 0; ci0 < 256; ci0 += 64) {
        __syncthreads();
        for (int idx = t; idx < 130 * 8; idx += 256) {
            int r = idx >> 3, c = idx & 7;
            int gl = l0 - 1 + r;
            short8 o;
            if (FIR) {
                float a8[8] = {};
                if (gl >= 0 && gl < L) {
                    #pragma unroll
                    for (int i = 0; i < 4; ++i) {
                        int rr = gl - pad + i;
                        if (rr >= 0 && rr < LinT) {
                            short8 v = *(const short8*)&Tb[(size_t)rr * 256 + ci0 + c * 8];
                            #pragma unroll
                            for (int j = 0; j < 8; ++j) a8[j] += cf[i] * bf2f((ushort)v[j]);
                        }
                    }
                    const float4* sv = (const float4*)&scale[b * CIN + ci0 + c * 8];
                    float4 s0 = sv[0], s1 = sv[1];
                    a8[0] *= s0.x; a8[1] *= s0.y; a8[2] *= s0.z; a8[3] *= s0.w;
                    a8[4] *= s1.x; a8[5] *= s1.y; a8[6] *= s1.z; a8[7] *= s1.w;
                }
                #pragma unroll
                for (int j = 0; j < 8; ++j) o[j] = (short)f2bf(a8[j]);
            } else {
                o = *(const short8*)(Tb + (ptrdiff_t)gl * 256 + ci0 + c * 8);
            }
            *(short8*)&Xs[r * 64 + ((c * 8) ^ ((r & 7) * 8))] = o;
        }
        __syncthreads();
        #pragma unroll
        for (int tap = 0; tap < 3; ++tap)
            #pragma unroll
            for (int kk = 0; kk < 2; ++kk) {
                short8 a[4];
                #pragma unroll
                for (int mf = 0; mf < 4; ++mf)
                    a[mf] = *(const short8*)&Wl[(size_t)(cot + mf * 16 + lr) * 768 + tap * 256 + ci0 + kk * 32 + lg * 8];
                short8 bf[2];
                #pragma unroll
                for (int nf = 0; nf < 2; ++nf) {
                    int row = wv * 32 + nf * 16 + lr + tap;
                    int ci = kk * 32 + lg * 8;
                    bf[nf] = *(const short8*)&Xs[row * 64 + (ci ^ ((row & 7) * 8))];
                }
                #pragma unroll
                for (int mf = 0; mf < 4; ++mf)
                    #pragma unroll
                    for (int nf = 0; nf < 2; ++nf)
                        acc[mf][nf] = __builtin_amdgcn_mfma_f32_16x16x32_bf16(a[mf], bf[nf], acc[mf][nf], 0, 0, 0);
            }
    }

    // epilogue: LDS transpose to [l][co], coalesced bf16 stores (verified round 7)
    __syncthreads();
    ushort* Ot = Xs;   // 128 x 72
    #pragma unroll
    for (int mf = 0; mf < 4; ++mf)
        #pragma unroll
        for (int nf = 0; nf < 2; ++nf)
            #pragma unroll
            for (int rg = 0; rg < 4; ++rg) {
                int lo = wv * 32 + nf * 16 + lr;
                int co = mf * 16 + lg * 4 + rg;
                float dmv = dm[b * COUT + cot + co] * KSCALE;
                float v = acc[mf][nf][rg] * dmv + bias[cot + co];
                if (post) v *= post[b * COUT + cot + co] * KSCALE;
                Ot[lo * 72 + co] = f2bf(v);
            }
    __syncthreads();
    ushort* ob = Tout + (size_t)b * SRROW * 256;
    for (int idx = t; idx < 128 * 8; idx += 256) {
        int lo = idx >> 3, ch = idx & 7;
        short8 v = *(const short8*)&Ot[lo * 72 + ch * 8];
        *(short8*)&ob[(size_t)(l0 + lo) * 256 + cot + ch * 8] = v;
    }
}

// ================= transpose conv stride 2: 64o x 128m, K chunked =================
__global__ __launch_bounds__(256, 4) void upconv_mfma(
    const ushort* __restrict__ Tin, int Lout,
    const ushort* __restrict__ Wl,      // [tap][o][c]
    const float* __restrict__ s, const float* __restrict__ bias,
    ushort* __restrict__ Tout)
{
    __shared__ __align__(16) ushort Xs[9216];
    int m0 = blockIdx.x * 128;
    int ot = blockIdx.y * 64;
    int b = blockIdx.z;
    int t = threadIdx.x;
    int lane = t & 63, wv = t >> 6;
    int lr = lane & 15, lg = lane >> 4;

    const ushort* Tb = Tin + (size_t)b * SRROW * 256;

    floatx4 aE[4][2], aO[4][2];
    #pragma unroll
    for (int i = 0; i < 4; ++i)
        #pragma unroll
        for (int j = 0; j < 2; ++j) { aE[i][j] = (floatx4)0.f; aO[i][j] = (floatx4)0.f; }

    for (int ci0 = 0; ci0 < 256; ci0 += 64) {
        __syncthreads();
        for (int idx = t; idx < 130 * 8; idx += 256) {
            int r = idx >> 3, c = idx & 7;
            short8 v = *(const short8*)(Tb + (ptrdiff_t)(m0 - 1 + r) * 256 + ci0 + c * 8);
            *(short8*)&Xs[r * 64 + ((c * 8) ^ ((r & 7) * 8))] = v;
        }
        __syncthreads();
        #pragma unroll
        for (int kk = 0; kk < 2; ++kk) {
            short8 bm1[2], bm[2];
            #pragma unroll
            for (int nf = 0; nf < 2; ++nf) {
                int r0 = wv * 32 + nf * 16 + lr;
                int ci = kk * 32 + lg * 8;
                bm1[nf] = *(const short8*)&Xs[r0 * 64 + (ci ^ ((r0 & 7) * 8))];
                int r1 = r0 + 1;
                bm[nf]  = *(const short8*)&Xs[r1 * 64 + (ci ^ ((r1 & 7) * 8))];
            }
            #pragma unroll
            for (int tap = 0; tap < 3; ++tap) {
                short8 a[4];
                #pragma unroll
                for (int mf = 0; mf < 4; ++mf)
                    a[mf] = *(const short8*)&Wl[(size_t)tap * 65536 + (size_t)(ot + mf * 16 + lr) * 256 + ci0 + kk * 32 + lg * 8];
                #pragma unroll
                for (int mf = 0; mf < 4; ++mf)
                    #pragma unroll
                    for (int nf = 0; nf < 2; ++nf) {
                        if (tap == 0) aE[mf][nf] = __builtin_amdgcn_mfma_f32_16x16x32_bf16(a[mf], bm[nf],  aE[mf][nf], 0, 0, 0);
                        if (tap == 2) aE[mf][nf] = __builtin_amdgcn_mfma_f32_16x16x32_bf16(a[mf], bm1[nf], aE[mf][nf], 0, 0, 0);
                        if (tap == 1) aO[mf][nf] = __builtin_amdgcn_mfma_f32_16x16x32_bf16(a[mf], bm[nf],  aO[mf][nf], 0, 0, 0);
                    }
            }
        }
    }

    // epilogue in two 128-row passes (waves 0-1 then 2-3), Ot = 128x72
    ushort* Ot = Xs;
    ushort* ob = Tout + (size_t)b * SRROW * 256;
    __syncthreads();
    if (wv < 2) {
        #pragma unroll
        for (int mf = 0; mf < 4; ++mf)
            #pragma unroll
            for (int nf = 0; nf < 2; ++nf)
                #pragma unroll
                for (int rg = 0; rg < 4; ++rg) {
                    int mloc = wv * 32 + nf * 16 + lr;   // 0..63
                    int co = mf * 16 + lg * 4 + rg;
                    float sv = s[b * COUT + ot + co];
                    float bi = bias[ot + co];
                    Ot[(2 * mloc) * 72 + co]     = f2bf(aE[mf][nf][rg] * sv + bi);
                    Ot[(2 * mloc + 1) * 72 + co] = f2bf(aO[mf][nf][rg] * sv + bi);
                }
    }
    __syncthreads();
    for (int idx = t; idx < 128 * 8; idx += 256) {
        int lo = idx >> 3, ch = idx & 7;
        int n = 2 * m0 + lo;
        if (n < Lout) {
            short8 v = *(const short8*)&Ot[lo * 72 + ch * 8];
            *(short8*)&ob[(size_t)n * 256 + ot + ch * 8] = v;
        }
    }
    __syncthreads();
    if (wv >= 2) {
        #pragma unroll
        for (int mf = 0; mf < 4; ++mf)
            #pragma unroll
            for (int nf = 0; nf < 2; ++nf)
                #pragma unroll
                for (int rg = 0; rg < 4; ++rg) {
                    int mloc = wv * 32 + nf * 16 + lr;   // 64..127
                    int co = mf * 16 + lg * 4 + rg;
                    float sv = s[b * COUT + ot + co];
                    float bi = bias[ot + co];
                    Ot[(2 * mloc - 128) * 72 + co] = f2bf(aE[mf][nf][rg] * sv + bi);
                    Ot[(2 * mloc - 127) * 72 + co] = f2bf(aO[mf][nf][rg] * sv + bi);
                }
    }
    __syncthreads();
    for (int idx = t; idx < 128 * 8; idx += 256) {
        int lo = idx >> 3, ch = idx & 7;
        int n = 2 * m0 + 128 + lo;
        if (n < Lout) {
            short8 v = *(const short8*)&Ot[lo * 72 + ch * 8];
            *(short8*)&ob[(size_t)n * 256 + ot + ch * 8] = v;
        }
    }
}

// ================= stride-2 conv, blur2 fused in staging: 128co x 64l =================
// staged[gl][ci] = s3[ci] * sum_i cf[i]*T4[gl-2+i][ci]  (T4 rows valid [0,8192))
__global__ __launch_bounds__(256, 4) void conv_down_mfma(
    const ushort* __restrict__ Tin,
    const ushort* __restrict__ Wl,      // [co][768]
    const float* __restrict__ dm, const float* __restrict__ s3,
    const float* __restrict__ bias,
    float* __restrict__ outp)
{
    __shared__ __align__(16) ushort Xs[8320];   // 130 x 64
    int l0 = blockIdx.x * 64;
    int cot = blockIdx.y * 128;
    int b = blockIdx.z;
    int t = threadIdx.x;
    int lane = t & 63, wv = t >> 6;
    int wm = wv >> 1, wn = wv & 1;
    int lr = lane & 15, lg = lane >> 4;

    const ushort* Tb = Tin + (size_t)b * SRROW * 256;
    const float cf[4] = {0.125f, 0.375f, 0.375f, 0.125f};

    floatx4 acc[4][2];
    #pragma unroll
    for (int i = 0; i < 4; ++i) { acc[i][0] = (floatx4)0.f; acc[i][1] = (floatx4)0.f; }

    for (int ci0 = 0; ci0 < 256; ci0 += 64) {
        __syncthreads();
        for (int idx = t; idx < 130 * 8; idx += 256) {
            int r = idx >> 3, c = idx & 7;
            int gl = 2 * l0 + r;
            float a8[8] = {};
            #pragma unroll
            for (int i = 0; i < 4; ++i) {
                int rr = gl - 2 + i;
                if (rr >= 0 && rr < 8192) {
                    short8 v = *(const short8*)&Tb[(size_t)rr * 256 + ci0 + c * 8];
                    #pragma unroll
                    for (int j = 0; j < 8; ++j) a8[j] += cf[i] * bf2f((ushort)v[j]);
                }
            }
            const float4* sv = (const float4*)&s3[b * CIN + ci0 + c * 8];
            float4 s0 = sv[0], s1 = sv[1];
            a8[0] *= s0.x; a8[1] *= s0.y; a8[2] *= s0.z; a8[3] *= s0.w;
            a8[4] *= s1.x; a8[5] *= s1.y; a8[6] *= s1.z; a8[7] *= s1.w;
            short8 o;
            #pragma unroll
            for (int j = 0; j < 8; ++j) o[j] = (short)f2bf(a8[j]);
            *(short8*)&Xs[r * 64 + ((c * 8) ^ ((r & 7) * 8))] = o;
        }
        __syncthreads();
        #pragma unroll
        for (int tap = 0; tap < 3; ++tap)
            #pragma unroll
            for (int kk = 0; kk < 2; ++kk) {
                short8 a[4];
                #pragma unroll
                for (int mf = 0; mf < 4; ++mf)
                    a[mf] = *(const short8*)&Wl[(size_t)(cot + wm * 64 + mf * 16 + lr) * 768 + tap * 256 + ci0 + kk * 32 + lg * 8];
                short8 bf[2];
                #pragma unroll
                for (int nf = 0; nf < 2; ++nf) {
                    int row = 2 * (wn * 32 + nf * 16 + lr) + tap;
                    int ci = kk * 32 + lg * 8;
                    bf[nf] = *(const short8*)&Xs[row * 64 + (ci ^ ((row & 7) * 8))];
                }
                #pragma unroll
                for (int mf = 0; mf < 4; ++mf)
                    #pragma unroll
                    for (int nf = 0; nf < 2; ++nf)
                        acc[mf][nf] = __builtin_amdgcn_mfma_f32_16x16x32_bf16(a[mf], bf[nf], acc[mf][nf], 0, 0, 0);
            }
    }

    float* ob = outp + (size_t)b * COUT * 4096;
    #pragma unroll
    for (int mf = 0; mf < 4; ++mf)
        #pragma unroll
        for (int nf = 0; nf < 2; ++nf)
            #pragma unroll
            for (int rg = 0; rg < 4; ++rg) {
                int co = cot + wm * 64 + mf * 16 + lg * 4 + rg;
                int l = l0 + wn * 32 + nf * 16 + lr;
                float dmv = dm[b * COUT + co] * KSCALE;
                ob[(size_t)co * 4096 + l] = acc[mf][nf][rg] * dmv + bias[co];
            }
}

extern "C" void kernel_launch(void* const* d_in, const int* in_sizes, int n_in,
                              void* d_out, int out_size, void* d_ws, size_t ws_size,
                              hipStream_t stream) {
    const float* x       = (const float*)d_in[0];
    const float* style   = (const float*)d_in[1];
    const float* weights = (const float*)d_in[2];
    const float* biases  = (const float*)d_in[3];
    const float* mod_w   = (const float*)d_in[4];
    const float* mod_b   = (const float*)d_in[5];
    float* out = (float*)d_out;

    float* s_all = (float*)d_ws;                       // 4*16*256
    float* demod_all = s_all + 4 * NB * CIN;           // 4*16*256
    const size_t WBF_OFF = 131072;                     // bytes
    const size_t BUF_OFF = WBF_OFF + 1572864;          // + Wbf bytes
    ushort* Wbf = (ushort*)((char*)d_ws + WBF_OFF);
    ushort* bufBase = (ushort*)((char*)d_ws + BUF_OFF);

    const int SL = NB * CIN;
    const size_t perSampleB = (size_t)2 * SRROW * 256 * sizeof(ushort);
    size_t availB = ws_size > BUF_OFF ? ws_size - BUF_OFF : 0;
    int g = (int)(availB / perSampleB);
    if (g < 1) g = 1;
    if (g > NB) g = NB;

    const size_t sElems = (size_t)SRROW * 256;
    ushort* bufAU = bufBase;
    ushort* bufBU = bufBase + (size_t)g * sElems;
    ushort* bufA = bufAU + 256;                        // data row 0 (guard at underlying 0)
    ushort* bufB = bufBU + 256;

    mod_k<<<64, 256, 0, stream>>>(style, weights, mod_w, mod_b, s_all, demod_all);
    wprep_k<<<dim3(256, 4), 256, 0, stream>>>(weights, Wbf);

    for (int b0 = 0; b0 < NB; b0 += g) {
        int gb = NB - b0 < g ? NB - b0 : g;

        // T0 = bf16(x*s0) -> bufA ; guards at data {-1,4096} = underlying {0,4097}
        xprep_k<<<dim3(64, 4, gb), 256, 0, stream>>>(
            x + (size_t)b0 * CIN * 4096, s_all + 0 * SL + b0 * CIN, bufA);
        guard_k<<<gb, 256, 0, stream>>>(bufAU, 0, 4097);

        // conv0 (same, L=4096, plain staging): bufA -> bufB = T1 (post = dm1*KSCALE)
        conv_same_mfma<false><<<dim3(32, 4, gb), 256, 0, stream>>>(
            bufA, 4096, 0, Wbf + 0 * 196608,
            demod_all + 0 * SL + b0 * CIN, demod_all + 1 * SL + b0 * CIN,
            nullptr, biases + 0 * COUT, bufB, 0.f, 0.f, 0.f, 0.f, 0);
        guard_k<<<gb, 256, 0, stream>>>(bufBU, 0, 4097);

        // upconv: bufB -> bufA = T2 (8193 data rows, plain bf16)
        upconv_mfma<<<dim3(33, 4, gb), 256, 0, stream>>>(
            bufB, 8193, Wbf + 1 * 196608,
            s_all + 1 * SL + b0 * CIN, biases + 1 * COUT, bufA);

        // conv2 (same, L=8192, blur1+s2 fused in staging): bufA(T2) -> bufB = T4
        conv_same_mfma<true><<<dim3(64, 4, gb), 256, 0, stream>>>(
            bufA, 8192, 8193, Wbf + 2 * 196608,
            demod_all + 2 * SL + b0 * CIN, nullptr,
            s_all + 2 * SL + b0 * CIN, biases + 2 * COUT, bufB,
            0.25f, 0.75f, 0.75f, 0.25f, 1);

        // conv3 (down, blur2+s3 fused in staging): bufB(T4) -> out f32
        conv_down_mfma<<<dim3(64, 2, gb), 256, 0, stream>>>(
            bufB, Wbf + 3 * 196608,
            demod_all + 3 * SL + b0 * CIN, s_all + 3 * SL + b0 * CIN,
            biases + 3 * COUT, out + (size_t)b0 * COUT * 4096);
    }
}

// Round 9
// 592.080 us; speedup vs baseline: 5.7557x; 1.1904x over previous
//
#include <hip/hip_runtime.h>
#include <math.h>
#include <stddef.h>

#define CIN 256
#define COUT 256
#define SD 512
#define NB 16
#define KSCALE (1.0f / 48.0f)   // 1/sqrt(256*9)
#define MEPS 1e-8f
#define SRROW 8320               // per-sample row stride (rows of 256 bf16)

typedef __attribute__((ext_vector_type(8))) short short8;
typedef __attribute__((ext_vector_type(4))) float floatx4;
typedef unsigned short ushort;

__device__ inline ushort f2bf(float f) {
    union { float f; unsigned int u; } v; v.f = f;
    unsigned int u = v.u;
    return (ushort)((u + 0x7FFFu + ((u >> 16) & 1u)) >> 16);
}
__device__ inline float bf2f(ushort h) {
    union { unsigned int u; float f; } v; v.u = ((unsigned int)h) << 16;
    return v.f;
}

// ---------------- modulation (verified round 4-8) ----------------
__global__ __launch_bounds__(256) void mod_k(
    const float* __restrict__ style, const float* __restrict__ weights,
    const float* __restrict__ mod_w, const float* __restrict__ mod_b,
    float* __restrict__ s_all, float* __restrict__ demod_all)
{
    int layer = blockIdx.x >> 4;
    int b = blockIdx.x & 15;
    int t = threadIdx.x;
    __shared__ float st[SD];
    __shared__ float s2[CIN];

    for (int j = t; j < SD; j += 256) st[j] = style[b * SD + j];
    __syncthreads();

    const float* mw = mod_w + ((size_t)layer * CIN + t) * SD;
    float acc = 0.f;
    for (int j = 0; j < SD; ++j) acc += mw[j] * st[j];
    float s = acc + mod_b[layer * CIN + t];
    s_all[((size_t)layer * NB + b) * CIN + t] = s;
    s2[t] = s * s;
    __syncthreads();

    const float* wr = weights + ((size_t)layer * COUT + t) * (CIN * 3);
    float d = 0.f;
    for (int ci = 0; ci < CIN; ++ci) {
        float w0 = wr[ci * 3 + 0], w1 = wr[ci * 3 + 1], w2 = wr[ci * 3 + 2];
        d += (w0 * w0 + w1 * w1 + w2 * w2) * s2[ci];
    }
    demod_all[((size_t)layer * NB + b) * CIN + t] = rsqrtf(KSCALE * KSCALE * d + MEPS);
}

// ---------------- weight prep (verified round 7/8) ----------------
__global__ __launch_bounds__(256) void wprep_k(
    const float* __restrict__ weights, ushort* __restrict__ Wbf)
{
    int layer = blockIdx.y;
    int idx = blockIdx.x * 256 + threadIdx.x;
    int a = idx >> 8, c = idx & 255;
    ushort* wl = Wbf + (size_t)layer * 196608;
    if (layer == 1) {
        const float* src = weights + ((size_t)1 * 196608) + ((size_t)c * 256 + a) * 3;
        #pragma unroll
        for (int k = 0; k < 3; ++k)
            wl[(size_t)k * 65536 + a * 256 + c] = f2bf(src[k]);
    } else {
        const float* src = weights + ((size_t)layer * 196608) + ((size_t)a * 256 + c) * 3;
        #pragma unroll
        for (int k = 0; k < 3; ++k)
            wl[(size_t)a * 768 + k * 256 + c] = f2bf(src[k]);
    }
}

// ---------------- x prep (verified round 7/8) ----------------
__global__ __launch_bounds__(256) void xprep_k(
    const float* __restrict__ x, const float* __restrict__ s0,
    ushort* __restrict__ Tout)
{
    __shared__ ushort lt[64 * 72];
    int l0 = blockIdx.x * 64, ci0 = blockIdx.y * 64;
    int b = blockIdx.z;
    int t = threadIdx.x;
    const float* xb = x + (size_t)b * CIN * 4096;
    const float* sb = s0 + b * CIN;

    for (int idx = t; idx < 64 * 64; idx += 256) {
        int ci = idx >> 6, lc = idx & 63;
        float v = xb[(size_t)(ci0 + ci) * 4096 + l0 + lc] * sb[ci0 + ci];
        lt[lc * 72 + ci] = f2bf(v);
    }
    __syncthreads();
    ushort* ob = Tout + (size_t)b * SRROW * 256;
    for (int idx = t; idx < 64 * 8; idx += 256) {
        int lc = idx >> 3, ch = idx & 7;
        short8 v = *(const short8*)&lt[lc * 72 + ch * 8];
        *(short8*)&ob[(size_t)(l0 + lc) * 256 + ci0 + ch * 8] = v;
    }
}

// ---------------- zero guard rows (UNDERLYING coords; verified) -----------
__global__ __launch_bounds__(256) void guard_k(
    ushort* __restrict__ T, int rowA, int rowB)
{
    int b = blockIdx.x;
    ushort* base = T + (size_t)b * SRROW * 256;
    base[(size_t)rowA * 256 + threadIdx.x] = 0;
    base[(size_t)rowB * 256 + threadIdx.x] = 0;
}

// ================= conv same: 64co x 128l, K chunked by 64 ci, W in LDS =================
// FIR=true: staged value = scale[ci] * sum_i cf[i]*Tin[gl-pad+i][ci]  (blur fused)
// FIR=false: staged value = Tin[gl][ci] (relies on guard rows at -1 / L)
template<bool FIR>
__global__ __launch_bounds__(256, 3) void conv_same_mfma(
    const ushort* __restrict__ Tin, int L, int LinT,
    const ushort* __restrict__ Wl,      // [co][768]
    const float* __restrict__ dm, const float* __restrict__ post,
    const float* __restrict__ scale, const float* __restrict__ bias,
    ushort* __restrict__ Tout,
    float c0, float c1, float c2, float c3, int pad)
{
    __shared__ __align__(16) ushort Xs[9216];    // X chunk 130x64 swz / epilogue 128x72
    __shared__ __align__(16) ushort Ws[12288];   // W chunk [tap][co][64] swz (24.6 KB)
    int l0 = blockIdx.x * 128;
    int cot = blockIdx.y * 64;
    int b = blockIdx.z;
    int t = threadIdx.x;
    int lane = t & 63, wv = t >> 6;
    int lr = lane & 15, lg = lane >> 4;

    const ushort* Tb = Tin + (size_t)b * SRROW * 256;
    float cf[4] = {c0, c1, c2, c3};

    floatx4 acc[4][2];
    #pragma unroll
    for (int i = 0; i < 4; ++i) { acc[i][0] = (floatx4)0.f; acc[i][1] = (floatx4)0.f; }

    for (int ci0 = 0; ci0 < 256; ci0 += 64) {
        __syncthreads();
        // ---- stage W chunk: 64co x 3tap x 64ci, swizzled rows ----
        for (int idx = t; idx < 1536; idx += 256) {
            int co = idx / 24, rem = idx % 24;
            int tap = rem >> 3, c = rem & 7;
            short8 v = *(const short8*)&Wl[(size_t)(cot + co) * 768 + tap * 256 + ci0 + c * 8];
            *(short8*)&Ws[(tap * 64 + co) * 64 + ((c * 8) ^ ((co & 7) * 8))] = v;
        }
        // ---- stage X chunk ----
        for (int idx = t; idx < 130 * 8; idx += 256) {
            int r = idx >> 3, c = idx & 7;
            int gl = l0 - 1 + r;
            short8 o;
            if (FIR) {
                float a8[8] = {};
                if (gl >= 0 && gl < L) {
                    #pragma unroll
                    for (int i = 0; i < 4; ++i) {
                        int rr = gl - pad + i;
                        if (rr >= 0 && rr < LinT) {
                            short8 v = *(const short8*)&Tb[(size_t)rr * 256 + ci0 + c * 8];
                            #pragma unroll
                            for (int j = 0; j < 8; ++j) a8[j] += cf[i] * bf2f((ushort)v[j]);
                        }
                    }
                    const float4* sv = (const float4*)&scale[b * CIN + ci0 + c * 8];
                    float4 s0 = sv[0], s1 = sv[1];
                    a8[0] *= s0.x; a8[1] *= s0.y; a8[2] *= s0.z; a8[3] *= s0.w;
                    a8[4] *= s1.x; a8[5] *= s1.y; a8[6] *= s1.z; a8[7] *= s1.w;
                }
                #pragma unroll
                for (int j = 0; j < 8; ++j) o[j] = (short)f2bf(a8[j]);
            } else {
                o = *(const short8*)(Tb + (ptrdiff_t)gl * 256 + ci0 + c * 8);
            }
            *(short8*)&Xs[r * 64 + ((c * 8) ^ ((r & 7) * 8))] = o;
        }
        __syncthreads();
        // ---- MFMA: A from Ws (LDS), B from Xs (LDS) ----
        #pragma unroll
        for (int tap = 0; tap < 3; ++tap)
            #pragma unroll
            for (int kk = 0; kk < 2; ++kk) {
                short8 a[4];
                #pragma unroll
                for (int mf = 0; mf < 4; ++mf)
                    a[mf] = *(const short8*)&Ws[(tap * 64 + mf * 16 + lr) * 64 + ((kk * 32 + lg * 8) ^ ((lr & 7) * 8))];
                short8 bf[2];
                #pragma unroll
                for (int nf = 0; nf < 2; ++nf) {
                    int row = wv * 32 + nf * 16 + lr + tap;
                    int ci = kk * 32 + lg * 8;
                    bf[nf] = *(const short8*)&Xs[row * 64 + (ci ^ ((row & 7) * 8))];
                }
                #pragma unroll
                for (int mf = 0; mf < 4; ++mf)
                    #pragma unroll
                    for (int nf = 0; nf < 2; ++nf)
                        acc[mf][nf] = __builtin_amdgcn_mfma_f32_16x16x32_bf16(a[mf], bf[nf], acc[mf][nf], 0, 0, 0);
            }
    }

    // epilogue: LDS transpose to [l][co], coalesced bf16 stores (verified)
    __syncthreads();
    ushort* Ot = Xs;   // 128 x 72
    #pragma unroll
    for (int mf = 0; mf < 4; ++mf)
        #pragma unroll
        for (int nf = 0; nf < 2; ++nf)
            #pragma unroll
            for (int rg = 0; rg < 4; ++rg) {
                int lo = wv * 32 + nf * 16 + lr;
                int co = mf * 16 + lg * 4 + rg;
                float dmv = dm[b * COUT + cot + co] * KSCALE;
                float v = acc[mf][nf][rg] * dmv + bias[cot + co];
                if (post) v *= post[b * COUT + cot + co] * KSCALE;
                Ot[lo * 72 + co] = f2bf(v);
            }
    __syncthreads();
    ushort* ob = Tout + (size_t)b * SRROW * 256;
    for (int idx = t; idx < 128 * 8; idx += 256) {
        int lo = idx >> 3, ch = idx & 7;
        short8 v = *(const short8*)&Ot[lo * 72 + ch * 8];
        *(short8*)&ob[(size_t)(l0 + lo) * 256 + cot + ch * 8] = v;
    }
}

// ================= transpose conv stride 2: 64o x 128m, K chunked, W in LDS =========
__global__ __launch_bounds__(256, 3) void upconv_mfma(
    const ushort* __restrict__ Tin, int Lout,
    const ushort* __restrict__ Wl,      // [tap][o][c]
    const float* __restrict__ s, const float* __restrict__ bias,
    ushort* __restrict__ Tout)
{
    __shared__ __align__(16) ushort Xs[9216];
    __shared__ __align__(16) ushort Ws[12288];
    int m0 = blockIdx.x * 128;
    int ot = blockIdx.y * 64;
    int b = blockIdx.z;
    int t = threadIdx.x;
    int lane = t & 63, wv = t >> 6;
    int lr = lane & 15, lg = lane >> 4;

    const ushort* Tb = Tin + (size_t)b * SRROW * 256;

    floatx4 aE[4][2], aO[4][2];
    #pragma unroll
    for (int i = 0; i < 4; ++i)
        #pragma unroll
        for (int j = 0; j < 2; ++j) { aE[i][j] = (floatx4)0.f; aO[i][j] = (floatx4)0.f; }

    for (int ci0 = 0; ci0 < 256; ci0 += 64) {
        __syncthreads();
        for (int idx = t; idx < 1536; idx += 256) {
            int o = idx / 24, rem = idx % 24;
            int tap = rem >> 3, c = rem & 7;
            short8 v = *(const short8*)&Wl[(size_t)tap * 65536 + (size_t)(ot + o) * 256 + ci0 + c * 8];
            *(short8*)&Ws[(tap * 64 + o) * 64 + ((c * 8) ^ ((o & 7) * 8))] = v;
        }
        for (int idx = t; idx < 130 * 8; idx += 256) {
            int r = idx >> 3, c = idx & 7;
            short8 v = *(const short8*)(Tb + (ptrdiff_t)(m0 - 1 + r) * 256 + ci0 + c * 8);
            *(short8*)&Xs[r * 64 + ((c * 8) ^ ((r & 7) * 8))] = v;
        }
        __syncthreads();
        #pragma unroll
        for (int kk = 0; kk < 2; ++kk) {
            short8 bm1[2], bm[2];
            #pragma unroll
            for (int nf = 0; nf < 2; ++nf) {
                int r0 = wv * 32 + nf * 16 + lr;
                int ci = kk * 32 + lg * 8;
                bm1[nf] = *(const short8*)&Xs[r0 * 64 + (ci ^ ((r0 & 7) * 8))];
                int r1 = r0 + 1;
                bm[nf]  = *(const short8*)&Xs[r1 * 64 + (ci ^ ((r1 & 7) * 8))];
            }
            #pragma unroll
            for (int tap = 0; tap < 3; ++tap) {
                short8 a[4];
                #pragma unroll
                for (int mf = 0; mf < 4; ++mf)
                    a[mf] = *(const short8*)&Ws[(tap * 64 + mf * 16 + lr) * 64 + ((kk * 32 + lg * 8) ^ ((lr & 7) * 8))];
                #pragma unroll
                for (int mf = 0; mf < 4; ++mf)
                    #pragma unroll
                    for (int nf = 0; nf < 2; ++nf) {
                        if (tap == 0) aE[mf][nf] = __builtin_amdgcn_mfma_f32_16x16x32_bf16(a[mf], bm[nf],  aE[mf][nf], 0, 0, 0);
                        if (tap == 2) aE[mf][nf] = __builtin_amdgcn_mfma_f32_16x16x32_bf16(a[mf], bm1[nf], aE[mf][nf], 0, 0, 0);
                        if (tap == 1) aO[mf][nf] = __builtin_amdgcn_mfma_f32_16x16x32_bf16(a[mf], bm[nf],  aO[mf][nf], 0, 0, 0);
                    }
            }
        }
    }

    // epilogue in two 128-row passes (verified round 8)
    ushort* Ot = Xs;
    ushort* ob = Tout + (size_t)b * SRROW * 256;
    __syncthreads();
    if (wv < 2) {
        #pragma unroll
        for (int mf = 0; mf < 4; ++mf)
            #pragma unroll
            for (int nf = 0; nf < 2; ++nf)
                #pragma unroll
                for (int rg = 0; rg < 4; ++rg) {
                    int mloc = wv * 32 + nf * 16 + lr;   // 0..63
                    int co = mf * 16 + lg * 4 + rg;
                    float sv = s[b * COUT + ot + co];
                    float bi = bias[ot + co];
                    Ot[(2 * mloc) * 72 + co]     = f2bf(aE[mf][nf][rg] * sv + bi);
                    Ot[(2 * mloc + 1) * 72 + co] = f2bf(aO[mf][nf][rg] * sv + bi);
                }
    }
    __syncthreads();
    for (int idx = t; idx < 128 * 8; idx += 256) {
        int lo = idx >> 3, ch = idx & 7;
        int n = 2 * m0 + lo;
        if (n < Lout) {
            short8 v = *(const short8*)&Ot[lo * 72 + ch * 8];
            *(short8*)&ob[(size_t)n * 256 + ot + ch * 8] = v;
        }
    }
    __syncthreads();
    if (wv >= 2) {
        #pragma unroll
        for (int mf = 0; mf < 4; ++mf)
            #pragma unroll
            for (int nf = 0; nf < 2; ++nf)
                #pragma unroll
                for (int rg = 0; rg < 4; ++rg) {
                    int mloc = wv * 32 + nf * 16 + lr;   // 64..127
                    int co = mf * 16 + lg * 4 + rg;
                    float sv = s[b * COUT + ot + co];
                    float bi = bias[ot + co];
                    Ot[(2 * mloc - 128) * 72 + co] = f2bf(aE[mf][nf][rg] * sv + bi);
                    Ot[(2 * mloc - 127) * 72 + co] = f2bf(aO[mf][nf][rg] * sv + bi);
                }
    }
    __syncthreads();
    for (int idx = t; idx < 128 * 8; idx += 256) {
        int lo = idx >> 3, ch = idx & 7;
        int n = 2 * m0 + 128 + lo;
        if (n < Lout) {
            short8 v = *(const short8*)&Ot[lo * 72 + ch * 8];
            *(short8*)&ob[(size_t)n * 256 + ot + ch * 8] = v;
        }
    }
}

// ================= stride-2 conv, blur2 fused: 64co x 64l, W in LDS =================
// staged[gl][ci] = s3[ci] * sum_i cf[i]*T4[gl-2+i][ci]  (T4 rows valid [0,8192))
__global__ __launch_bounds__(256, 3) void conv_down_mfma(
    const ushort* __restrict__ Tin,
    const ushort* __restrict__ Wl,      // [co][768]
    const float* __restrict__ dm, const float* __restrict__ s3,
    const float* __restrict__ bias,
    float* __restrict__ outp)
{
    __shared__ __align__(16) ushort Xs[8320];    // 130 x 64 swz
    __shared__ __align__(16) ushort Ws[12288];
    int l0 = blockIdx.x * 64;
    int cot = blockIdx.y * 64;
    int b = blockIdx.z;
    int t = threadIdx.x;
    int lane = t & 63, wv = t >> 6;
    int wm = wv >> 1, wn = wv & 1;
    int lr = lane & 15, lg = lane >> 4;

    const ushort* Tb = Tin + (size_t)b * SRROW * 256;
    const float cf[4] = {0.125f, 0.375f, 0.375f, 0.125f};

    floatx4 acc[2][2];
    #pragma unroll
    for (int i = 0; i < 2; ++i) { acc[i][0] = (floatx4)0.f; acc[i][1] = (floatx4)0.f; }

    for (int ci0 = 0; ci0 < 256; ci0 += 64) {
        __syncthreads();
        for (int idx = t; idx < 1536; idx += 256) {
            int co = idx / 24, rem = idx % 24;
            int tap = rem >> 3, c = rem & 7;
            short8 v = *(const short8*)&Wl[(size_t)(cot + co) * 768 + tap * 256 + ci0 + c * 8];
            *(short8*)&Ws[(tap * 64 + co) * 64 + ((c * 8) ^ ((co & 7) * 8))] = v;
        }
        for (int idx = t; idx < 130 * 8; idx += 256) {
            int r = idx >> 3, c = idx & 7;
            int gl = 2 * l0 + r;
            float a8[8] = {};
            #pragma unroll
            for (int i = 0; i < 4; ++i) {
                int rr = gl - 2 + i;
                if (rr >= 0 && rr < 8192) {
                    short8 v = *(const short8*)&Tb[(size_t)rr * 256 + ci0 + c * 8];
                    #pragma unroll
                    for (int j = 0; j < 8; ++j) a8[j] += cf[i] * bf2f((ushort)v[j]);
                }
            }
            const float4* sv = (const float4*)&s3[b * CIN + ci0 + c * 8];
            float4 s0 = sv[0], s1 = sv[1];
            a8[0] *= s0.x; a8[1] *= s0.y; a8[2] *= s0.z; a8[3] *= s0.w;
            a8[4] *= s1.x; a8[5] *= s1.y; a8[6] *= s1.z; a8[7] *= s1.w;
            short8 o;
            #pragma unroll
            for (int j = 0; j < 8; ++j) o[j] = (short)f2bf(a8[j]);
            *(short8*)&Xs[r * 64 + ((c * 8) ^ ((r & 7) * 8))] = o;
        }
        __syncthreads();
        #pragma unroll
        for (int tap = 0; tap < 3; ++tap)
            #pragma unroll
            for (int kk = 0; kk < 2; ++kk) {
                short8 a[2];
                #pragma unroll
                for (int mf = 0; mf < 2; ++mf)
                    a[mf] = *(const short8*)&Ws[(tap * 64 + wm * 32 + mf * 16 + lr) * 64 + ((kk * 32 + lg * 8) ^ ((lr & 7) * 8))];
                short8 bf[2];
                #pragma unroll
                for (int nf = 0; nf < 2; ++nf) {
                    int row = 2 * (wn * 32 + nf * 16 + lr) + tap;
                    int ci = kk * 32 + lg * 8;
                    bf[nf] = *(const short8*)&Xs[row * 64 + (ci ^ ((row & 7) * 8))];
                }
                #pragma unroll
                for (int mf = 0; mf < 2; ++mf)
                    #pragma unroll
                    for (int nf = 0; nf < 2; ++nf)
                        acc[mf][nf] = __builtin_amdgcn_mfma_f32_16x16x32_bf16(a[mf], bf[nf], acc[mf][nf], 0, 0, 0);
            }
    }

    float* ob = outp + (size_t)b * COUT * 4096;
    #pragma unroll
    for (int mf = 0; mf < 2; ++mf)
        #pragma unroll
        for (int nf = 0; nf < 2; ++nf)
            #pragma unroll
            for (int rg = 0; rg < 4; ++rg) {
                int co = cot + wm * 32 + mf * 16 + lg * 4 + rg;
                int l = l0 + wn * 32 + nf * 16 + lr;
                float dmv = dm[b * COUT + co] * KSCALE;
                ob[(size_t)co * 4096 + l] = acc[mf][nf][rg] * dmv + bias[co];
            }
}

extern "C" void kernel_launch(void* const* d_in, const int* in_sizes, int n_in,
                              void* d_out, int out_size, void* d_ws, size_t ws_size,
                              hipStream_t stream) {
    const float* x       = (const float*)d_in[0];
    const float* style   = (const float*)d_in[1];
    const float* weights = (const float*)d_in[2];
    const float* biases  = (const float*)d_in[3];
    const float* mod_w   = (const float*)d_in[4];
    const float* mod_b   = (const float*)d_in[5];
    float* out = (float*)d_out;

    float* s_all = (float*)d_ws;                       // 4*16*256
    float* demod_all = s_all + 4 * NB * CIN;           // 4*16*256
    const size_t WBF_OFF = 131072;                     // bytes
    const size_t BUF_OFF = WBF_OFF + 1572864;          // + Wbf bytes
    ushort* Wbf = (ushort*)((char*)d_ws + WBF_OFF);
    ushort* bufBase = (ushort*)((char*)d_ws + BUF_OFF);

    const int SL = NB * CIN;
    const size_t perSampleB = (size_t)2 * SRROW * 256 * sizeof(ushort);
    size_t availB = ws_size > BUF_OFF ? ws_size - BUF_OFF : 0;
    int g = (int)(availB / perSampleB);
    if (g < 1) g = 1;
    if (g > NB) g = NB;

    const size_t sElems = (size_t)SRROW * 256;
    ushort* bufAU = bufBase;
    ushort* bufBU = bufBase + (size_t)g * sElems;
    ushort* bufA = bufAU + 256;                        // data row 0 (guard at underlying 0)
    ushort* bufB = bufBU + 256;

    mod_k<<<64, 256, 0, stream>>>(style, weights, mod_w, mod_b, s_all, demod_all);
    wprep_k<<<dim3(256, 4), 256, 0, stream>>>(weights, Wbf);

    for (int b0 = 0; b0 < NB; b0 += g) {
        int gb = NB - b0 < g ? NB - b0 : g;

        // T0 = bf16(x*s0) -> bufA ; guards at data {-1,4096} = underlying {0,4097}
        xprep_k<<<dim3(64, 4, gb), 256, 0, stream>>>(
            x + (size_t)b0 * CIN * 4096, s_all + 0 * SL + b0 * CIN, bufA);
        guard_k<<<gb, 256, 0, stream>>>(bufAU, 0, 4097);

        // conv0 (same, L=4096, plain staging): bufA -> bufB = T1 (post = dm1*KSCALE)
        conv_same_mfma<false><<<dim3(32, 4, gb), 256, 0, stream>>>(
            bufA, 4096, 0, Wbf + 0 * 196608,
            demod_all + 0 * SL + b0 * CIN, demod_all + 1 * SL + b0 * CIN,
            nullptr, biases + 0 * COUT, bufB, 0.f, 0.f, 0.f, 0.f, 0);
        guard_k<<<gb, 256, 0, stream>>>(bufBU, 0, 4097);

        // upconv: bufB -> bufA = T2 (8193 data rows, plain bf16)
        upconv_mfma<<<dim3(33, 4, gb), 256, 0, stream>>>(
            bufB, 8193, Wbf + 1 * 196608,
            s_all + 1 * SL + b0 * CIN, biases + 1 * COUT, bufA);

        // conv2 (same, L=8192, blur1+s2 fused in staging): bufA(T2) -> bufB = T4
        conv_same_mfma<true><<<dim3(64, 4, gb), 256, 0, stream>>>(
            bufA, 8192, 8193, Wbf + 2 * 196608,
            demod_all + 2 * SL + b0 * CIN, nullptr,
            s_all + 2 * SL + b0 * CIN, biases + 2 * COUT, bufB,
            0.25f, 0.75f, 0.75f, 0.25f, 1);

        // conv3 (down, blur2+s3 fused in staging): bufB(T4) -> out f32
        conv_down_mfma<<<dim3(64, 4, gb), 256, 0, stream>>>(
            bufB, Wbf + 3 * 196608,
            demod_all + 3 * SL + b0 * CIN, s_all + 3 * SL + b0 * CIN,
            biases + 3 * COUT, out + (size_t)b0 * COUT * 4096);
    }
}

// Round 10
// 313.177 us; speedup vs baseline: 10.8815x; 1.8906x over previous
//
#include <hip/hip_runtime.h>
#include <math.h>
#include <stddef.h>

#define CIN 256
#define COUT 256
#define SD 512
#define NB 16
#define KSCALE (1.0f / 48.0f)   // 1/sqrt(256*9)
#define MEPS 1e-8f
#define SRROW 8320               // per-sample row stride (rows of 256 bf16)

typedef __attribute__((ext_vector_type(8))) short short8;
typedef __attribute__((ext_vector_type(4))) float floatx4;
typedef unsigned short ushort;

__device__ inline ushort f2bf(float f) {
    union { float f; unsigned int u; } v; v.f = f;
    unsigned int u = v.u;
    return (ushort)((u + 0x7FFFu + ((u >> 16) & 1u)) >> 16);
}
__device__ inline float bf2f(ushort h) {
    union { unsigned int u; float f; } v; v.u = ((unsigned int)h) << 16;
    return v.f;
}

// async global->LDS, 16B per lane; LDS dest is wave-uniform base + lane*16
__device__ inline void gload16(const ushort* g, ushort* l) {
    __builtin_amdgcn_global_load_lds(
        (const __attribute__((address_space(1))) unsigned int*)g,
        (__attribute__((address_space(3))) unsigned int*)l,
        16, 0, 0);
}

// ---------------- modulation (verified round 4-9) ----------------
__global__ __launch_bounds__(256) void mod_k(
    const float* __restrict__ style, const float* __restrict__ weights,
    const float* __restrict__ mod_w, const float* __restrict__ mod_b,
    float* __restrict__ s_all, float* __restrict__ demod_all)
{
    int layer = blockIdx.x >> 4;
    int b = blockIdx.x & 15;
    int t = threadIdx.x;
    __shared__ float st[SD];
    __shared__ float s2[CIN];

    for (int j = t; j < SD; j += 256) st[j] = style[b * SD + j];
    __syncthreads();

    const float* mw = mod_w + ((size_t)layer * CIN + t) * SD;
    float acc = 0.f;
    for (int j = 0; j < SD; ++j) acc += mw[j] * st[j];
    float s = acc + mod_b[layer * CIN + t];
    s_all[((size_t)layer * NB + b) * CIN + t] = s;
    s2[t] = s * s;
    __syncthreads();

    const float* wr = weights + ((size_t)layer * COUT + t) * (CIN * 3);
    float d = 0.f;
    for (int ci = 0; ci < CIN; ++ci) {
        float w0 = wr[ci * 3 + 0], w1 = wr[ci * 3 + 1], w2 = wr[ci * 3 + 2];
        d += (w0 * w0 + w1 * w1 + w2 * w2) * s2[ci];
    }
    demod_all[((size_t)layer * NB + b) * CIN + t] = rsqrtf(KSCALE * KSCALE * d + MEPS);
}

// ---------------- weight prep (verified round 7-9) ----------------
__global__ __launch_bounds__(256) void wprep_k(
    const float* __restrict__ weights, ushort* __restrict__ Wbf)
{
    int layer = blockIdx.y;
    int idx = blockIdx.x * 256 + threadIdx.x;
    int a = idx >> 8, c = idx & 255;
    ushort* wl = Wbf + (size_t)layer * 196608;
    if (layer == 1) {
        const float* src = weights + ((size_t)1 * 196608) + ((size_t)c * 256 + a) * 3;
        #pragma unroll
        for (int k = 0; k < 3; ++k)
            wl[(size_t)k * 65536 + a * 256 + c] = f2bf(src[k]);
    } else {
        const float* src = weights + ((size_t)layer * 196608) + ((size_t)a * 256 + c) * 3;
        #pragma unroll
        for (int k = 0; k < 3; ++k)
            wl[(size_t)a * 768 + k * 256 + c] = f2bf(src[k]);
    }
}

// ---------------- x prep (verified round 7-9) ----------------
__global__ __launch_bounds__(256) void xprep_k(
    const float* __restrict__ x, const float* __restrict__ s0,
    ushort* __restrict__ Tout)
{
    __shared__ ushort lt[64 * 72];
    int l0 = blockIdx.x * 64, ci0 = blockIdx.y * 64;
    int b = blockIdx.z;
    int t = threadIdx.x;
    const float* xb = x + (size_t)b * CIN * 4096;
    const float* sb = s0 + b * CIN;

    for (int idx = t; idx < 64 * 64; idx += 256) {
        int ci = idx >> 6, lc = idx & 63;
        float v = xb[(size_t)(ci0 + ci) * 4096 + l0 + lc] * sb[ci0 + ci];
        lt[lc * 72 + ci] = f2bf(v);
    }
    __syncthreads();
    ushort* ob = Tout + (size_t)b * SRROW * 256;
    for (int idx = t; idx < 64 * 8; idx += 256) {
        int lc = idx >> 3, ch = idx & 7;
        short8 v = *(const short8*)&lt[lc * 72 + ch * 8];
        *(short8*)&ob[(size_t)(l0 + lc) * 256 + ci0 + ch * 8] = v;
    }
}

// ---------------- zero guard rows (UNDERLYING coords; verified) -----------
__global__ __launch_bounds__(256) void guard_k(
    ushort* __restrict__ T, int rowA, int rowB)
{
    int b = blockIdx.x;
    ushort* base = T + (size_t)b * SRROW * 256;
    base[(size_t)rowA * 256 + threadIdx.x] = 0;
    base[(size_t)rowB * 256 + threadIdx.x] = 0;
}

// ---------------- bf16 blur (channel-last) + per-ci scale fold (round 4/6 semantics) ---
__global__ __launch_bounds__(256) void blur_bf16_k(
    const ushort* __restrict__ in, int Lin,
    ushort* __restrict__ outp, int Lout,
    const float* __restrict__ scale,   // [b][256]
    int pad, float c0, float c1, float c2, float c3)
{
    int b = blockIdx.y;
    int idx = blockIdx.x * 256 + threadIdx.x;
    if (idx >= Lout * 32) return;
    int row = idx >> 5, ci = (idx & 31) * 8;
    const ushort* ib = in + (size_t)b * SRROW * 256;
    float acc[8] = {};
    int base = row - pad;
    float cf[4] = {c0, c1, c2, c3};
    #pragma unroll
    for (int i = 0; i < 4; ++i) {
        int r = base + i;
        if (r >= 0 && r < Lin) {
            short8 v = *(const short8*)&ib[(size_t)r * 256 + ci];
            #pragma unroll
            for (int j = 0; j < 8; ++j) acc[j] += cf[i] * bf2f((ushort)v[j]);
        }
    }
    short8 o;
    #pragma unroll
    for (int j = 0; j < 8; ++j) {
        float sv = scale[b * CIN + ci + j];
        o[j] = (short)f2bf(acc[j] * sv);
    }
    *(short8*)&outp[((size_t)b * SRROW + row) * 256 + ci] = o;
}

// ================= conv same: 512 threads, 64co x 256l, K chunked by 64, gload_lds ======
// out[l][co] = bf16( (acc*dm[co]*KSCALE + bias[co]) * (post?post[co]*KSCALE:1) )
__global__ __launch_bounds__(512, 4) void conv_same_mfma(
    const ushort* __restrict__ Tin,
    const ushort* __restrict__ Wl,      // [co][768]
    const float* __restrict__ dm, const float* __restrict__ post,
    const float* __restrict__ bias,
    ushort* __restrict__ Tout)
{
    __shared__ __align__(16) ushort S[29184];   // Xs 264x64 (16896) | Ws 192x64 (12288)
    ushort* Xs = S;
    ushort* Ws = S + 16896;
    int l0 = blockIdx.x * 256;
    int cot = blockIdx.y * 64;
    int b = blockIdx.z;
    int t = threadIdx.x;
    int lane = t & 63, wv = t >> 6;             // 8 waves
    int lr = lane & 15, lg = lane >> 4;
    int lrow = lane >> 3, cg = lane & 7;

    const ushort* Tb = Tin + (size_t)b * SRROW * 256;

    floatx4 acc[4][2];
    #pragma unroll
    for (int i = 0; i < 4; ++i) { acc[i][0] = (floatx4)0.f; acc[i][1] = (floatx4)0.f; }

    for (int ci0 = 0; ci0 < 256; ci0 += 64) {
        __syncthreads();
        // W chunk: 24 issues of 8 rows (tap*64+co), source pre-swizzled, LDS linear
        for (int i = wv; i < 24; i += 8) {
            int wr = i * 8 + lrow;
            int co = wr & 63, tap = wr >> 6;
            gload16(Wl + (size_t)(cot + co) * 768 + tap * 256 + ci0 + ((cg ^ (co & 7)) * 8),
                    Ws + i * 512);
        }
        // X chunk: 33 issues cover rows l0-1 .. l0+262 (258 consumed)
        for (int i = wv; i < 33; i += 8) {
            int row = i * 8 + lrow;
            gload16(Tb + (ptrdiff_t)(l0 - 1 + row) * 256 + ci0 + ((cg ^ (row & 7)) * 8),
                    Xs + i * 512);
        }
        __syncthreads();   // drains vmcnt (compiler-inserted)
        #pragma unroll
        for (int tap = 0; tap < 3; ++tap)
            #pragma unroll
            for (int kk = 0; kk < 2; ++kk) {
                short8 a[4];
                #pragma unroll
                for (int mf = 0; mf < 4; ++mf)
                    a[mf] = *(const short8*)&Ws[(tap * 64 + mf * 16 + lr) * 64 + ((kk * 32 + lg * 8) ^ ((lr & 7) * 8))];
                short8 bf[2];
                #pragma unroll
                for (int nf = 0; nf < 2; ++nf) {
                    int row = wv * 32 + nf * 16 + lr + tap;
                    bf[nf] = *(const short8*)&Xs[row * 64 + ((kk * 32 + lg * 8) ^ ((row & 7) * 8))];
                }
                #pragma unroll
                for (int mf = 0; mf < 4; ++mf)
                    #pragma unroll
                    for (int nf = 0; nf < 2; ++nf)
                        acc[mf][nf] = __builtin_amdgcn_mfma_f32_16x16x32_bf16(a[mf], bf[nf], acc[mf][nf], 0, 0, 0);
            }
    }

    // epilogue: LDS transpose to [l][co], coalesced bf16 stores (round 7-9 pattern)
    __syncthreads();
    ushort* Ot = S;   // 256 x 72 = 18432 <= 29184
    #pragma unroll
    for (int mf = 0; mf < 4; ++mf)
        #pragma unroll
        for (int nf = 0; nf < 2; ++nf)
            #pragma unroll
            for (int rg = 0; rg < 4; ++rg) {
                int lo = wv * 32 + nf * 16 + lr;
                int co = mf * 16 + lg * 4 + rg;
                float dmv = dm[b * COUT + cot + co] * KSCALE;
                float v = acc[mf][nf][rg] * dmv + bias[cot + co];
                if (post) v *= post[b * COUT + cot + co] * KSCALE;
                Ot[lo * 72 + co] = f2bf(v);
            }
    __syncthreads();
    ushort* ob = Tout + (size_t)b * SRROW * 256;
    for (int idx = t; idx < 256 * 8; idx += 512) {
        int lo = idx >> 3, ch = idx & 7;
        short8 v = *(const short8*)&Ot[lo * 72 + ch * 8];
        *(short8*)&ob[(size_t)(l0 + lo) * 256 + cot + ch * 8] = v;
    }
}

// ================= transpose conv stride 2: 64o x 128m, gload_lds =================
__global__ __launch_bounds__(256, 3) void upconv_mfma(
    const ushort* __restrict__ Tin, int Lout,
    const ushort* __restrict__ Wl,      // [tap][o][c]
    const float* __restrict__ s, const float* __restrict__ bias,
    ushort* __restrict__ Tout)
{
    __shared__ __align__(16) ushort S[20992];   // Xs 136x64 (8704) | Ws 192x64 (12288)
    ushort* Xs = S;
    ushort* Ws = S + 8704;
    int m0 = blockIdx.x * 128;
    int ot = blockIdx.y * 64;
    int b = blockIdx.z;
    int t = threadIdx.x;
    int lane = t & 63, wv = t >> 6;
    int lr = lane & 15, lg = lane >> 4;
    int lrow = lane >> 3, cg = lane & 7;

    const ushort* Tb = Tin + (size_t)b * SRROW * 256;

    floatx4 aE[4][2], aO[4][2];
    #pragma unroll
    for (int i = 0; i < 4; ++i)
        #pragma unroll
        for (int j = 0; j < 2; ++j) { aE[i][j] = (floatx4)0.f; aO[i][j] = (floatx4)0.f; }

    for (int ci0 = 0; ci0 < 256; ci0 += 64) {
        __syncthreads();
        for (int i = wv; i < 24; i += 4) {
            int wr = i * 8 + lrow;
            int o = wr & 63, tap = wr >> 6;
            gload16(Wl + (size_t)tap * 65536 + (size_t)(ot + o) * 256 + ci0 + ((cg ^ (o & 7)) * 8),
                    Ws + i * 512);
        }
        for (int i = wv; i < 17; i += 4) {
            int row = i * 8 + lrow;
            gload16(Tb + (ptrdiff_t)(m0 - 1 + row) * 256 + ci0 + ((cg ^ (row & 7)) * 8),
                    Xs + i * 512);
        }
        __syncthreads();
        #pragma unroll
        for (int kk = 0; kk < 2; ++kk) {
            short8 bm1[2], bm[2];
            #pragma unroll
            for (int nf = 0; nf < 2; ++nf) {
                int r0 = wv * 32 + nf * 16 + lr;
                int ci = kk * 32 + lg * 8;
                bm1[nf] = *(const short8*)&Xs[r0 * 64 + (ci ^ ((r0 & 7) * 8))];
                int r1 = r0 + 1;
                bm[nf]  = *(const short8*)&Xs[r1 * 64 + (ci ^ ((r1 & 7) * 8))];
            }
            #pragma unroll
            for (int tap = 0; tap < 3; ++tap) {
                short8 a[4];
                #pragma unroll
                for (int mf = 0; mf < 4; ++mf)
                    a[mf] = *(const short8*)&Ws[(tap * 64 + mf * 16 + lr) * 64 + ((kk * 32 + lg * 8) ^ ((lr & 7) * 8))];
                #pragma unroll
                for (int mf = 0; mf < 4; ++mf)
                    #pragma unroll
                    for (int nf = 0; nf < 2; ++nf) {
                        if (tap == 0) aE[mf][nf] = __builtin_amdgcn_mfma_f32_16x16x32_bf16(a[mf], bm[nf],  aE[mf][nf], 0, 0, 0);
                        if (tap == 2) aE[mf][nf] = __builtin_amdgcn_mfma_f32_16x16x32_bf16(a[mf], bm1[nf], aE[mf][nf], 0, 0, 0);
                        if (tap == 1) aO[mf][nf] = __builtin_amdgcn_mfma_f32_16x16x32_bf16(a[mf], bm[nf],  aO[mf][nf], 0, 0, 0);
                    }
            }
        }
    }

    // epilogue in two 128-row passes (verified round 8/9), Ot = S (128x72)
    ushort* Ot = S;
    ushort* ob = Tout + (size_t)b * SRROW * 256;
    __syncthreads();
    if (wv < 2) {
        #pragma unroll
        for (int mf = 0; mf < 4; ++mf)
            #pragma unroll
            for (int nf = 0; nf < 2; ++nf)
                #pragma unroll
                for (int rg = 0; rg < 4; ++rg) {
                    int mloc = wv * 32 + nf * 16 + lr;   // 0..63
                    int co = mf * 16 + lg * 4 + rg;
                    float sv = s[b * COUT + ot + co];
                    float bi = bias[ot + co];
                    Ot[(2 * mloc) * 72 + co]     = f2bf(aE[mf][nf][rg] * sv + bi);
                    Ot[(2 * mloc + 1) * 72 + co] = f2bf(aO[mf][nf][rg] * sv + bi);
                }
    }
    __syncthreads();
    for (int idx = t; idx < 128 * 8; idx += 256) {
        int lo = idx >> 3, ch = idx & 7;
        int n = 2 * m0 + lo;
        if (n < Lout) {
            short8 v = *(const short8*)&Ot[lo * 72 + ch * 8];
            *(short8*)&ob[(size_t)n * 256 + ot + ch * 8] = v;
        }
    }
    __syncthreads();
    if (wv >= 2) {
        #pragma unroll
        for (int mf = 0; mf < 4; ++mf)
            #pragma unroll
            for (int nf = 0; nf < 2; ++nf)
                #pragma unroll
                for (int rg = 0; rg < 4; ++rg) {
                    int mloc = wv * 32 + nf * 16 + lr;   // 64..127
                    int co = mf * 16 + lg * 4 + rg;
                    float sv = s[b * COUT + ot + co];
                    float bi = bias[ot + co];
                    Ot[(2 * mloc - 128) * 72 + co] = f2bf(aE[mf][nf][rg] * sv + bi);
                    Ot[(2 * mloc - 127) * 72 + co] = f2bf(aO[mf][nf][rg] * sv + bi);
                }
    }
    __syncthreads();
    for (int idx = t; idx < 128 * 8; idx += 256) {
        int lo = idx >> 3, ch = idx & 7;
        int n = 2 * m0 + 128 + lo;
        if (n < Lout) {
            short8 v = *(const short8*)&Ot[lo * 72 + ch * 8];
            *(short8*)&ob[(size_t)n * 256 + ot + ch * 8] = v;
        }
    }
}

// ================= stride-2 conv: 64co x 64l, gload_lds =================
__global__ __launch_bounds__(256, 3) void conv_down_mfma(
    const ushort* __restrict__ Tin,
    const ushort* __restrict__ Wl,      // [co][768]
    const float* __restrict__ dm, const float* __restrict__ bias,
    float* __restrict__ outp)
{
    __shared__ __align__(16) ushort S[20992];   // Xs 136x64 | Ws 192x64
    ushort* Xs = S;
    ushort* Ws = S + 8704;
    int l0 = blockIdx.x * 64;
    int cot = blockIdx.y * 64;
    int b = blockIdx.z;
    int t = threadIdx.x;
    int lane = t & 63, wv = t >> 6;
    int wm = wv >> 1, wn = wv & 1;
    int lr = lane & 15, lg = lane >> 4;
    int lrow = lane >> 3, cg = lane & 7;

    const ushort* Tb = Tin + (size_t)b * SRROW * 256;

    floatx4 acc[2][2];
    #pragma unroll
    for (int i = 0; i < 2; ++i) { acc[i][0] = (floatx4)0.f; acc[i][1] = (floatx4)0.f; }

    for (int ci0 = 0; ci0 < 256; ci0 += 64) {
        __syncthreads();
        for (int i = wv; i < 24; i += 4) {
            int wr = i * 8 + lrow;
            int co = wr & 63, tap = wr >> 6;
            gload16(Wl + (size_t)(cot + co) * 768 + tap * 256 + ci0 + ((cg ^ (co & 7)) * 8),
                    Ws + i * 512);
        }
        for (int i = wv; i < 17; i += 4) {
            int row = i * 8 + lrow;
            gload16(Tb + (ptrdiff_t)(2 * l0 + row) * 256 + ci0 + ((cg ^ (row & 7)) * 8),
                    Xs + i * 512);
        }
        __syncthreads();
        #pragma unroll
        for (int tap = 0; tap < 3; ++tap)
            #pragma unroll
            for (int kk = 0; kk < 2; ++kk) {
                short8 a[2];
                #pragma unroll
                for (int mf = 0; mf < 2; ++mf)
                    a[mf] = *(const short8*)&Ws[(tap * 64 + wm * 32 + mf * 16 + lr) * 64 + ((kk * 32 + lg * 8) ^ ((lr & 7) * 8))];
                short8 bf[2];
                #pragma unroll
                for (int nf = 0; nf < 2; ++nf) {
                    int row = 2 * (wn * 32 + nf * 16 + lr) + tap;
                    bf[nf] = *(const short8*)&Xs[row * 64 + ((kk * 32 + lg * 8) ^ ((row & 7) * 8))];
                }
                #pragma unroll
                for (int mf = 0; mf < 2; ++mf)
                    #pragma unroll
                    for (int nf = 0; nf < 2; ++nf)
                        acc[mf][nf] = __builtin_amdgcn_mfma_f32_16x16x32_bf16(a[mf], bf[nf], acc[mf][nf], 0, 0, 0);
            }
    }

    float* ob = outp + (size_t)b * COUT * 4096;
    #pragma unroll
    for (int mf = 0; mf < 2; ++mf)
        #pragma unroll
        for (int nf = 0; nf < 2; ++nf)
            #pragma unroll
            for (int rg = 0; rg < 4; ++rg) {
                int co = cot + wm * 32 + mf * 16 + lg * 4 + rg;
                int l = l0 + wn * 32 + nf * 16 + lr;
                float dmv = dm[b * COUT + co] * KSCALE;
                ob[(size_t)co * 4096 + l] = acc[mf][nf][rg] * dmv + bias[co];
            }
}

extern "C" void kernel_launch(void* const* d_in, const int* in_sizes, int n_in,
                              void* d_out, int out_size, void* d_ws, size_t ws_size,
                              hipStream_t stream) {
    const float* x       = (const float*)d_in[0];
    const float* style   = (const float*)d_in[1];
    const float* weights = (const float*)d_in[2];
    const float* biases  = (const float*)d_in[3];
    const float* mod_w   = (const float*)d_in[4];
    const float* mod_b   = (const float*)d_in[5];
    float* out = (float*)d_out;

    float* s_all = (float*)d_ws;                       // 4*16*256
    float* demod_all = s_all + 4 * NB * CIN;           // 4*16*256
    const size_t WBF_OFF = 131072;                     // bytes
    const size_t BUF_OFF = WBF_OFF + 1572864;          // + Wbf bytes
    ushort* Wbf = (ushort*)((char*)d_ws + WBF_OFF);
    ushort* bufBase = (ushort*)((char*)d_ws + BUF_OFF);

    const int SL = NB * CIN;
    const size_t perSampleB = (size_t)2 * SRROW * 256 * sizeof(ushort);
    size_t availB = ws_size > BUF_OFF ? ws_size - BUF_OFF : 0;
    int g = (int)(availB / perSampleB);
    if (g < 1) g = 1;
    if (g > NB) g = NB;

    const size_t sElems = (size_t)SRROW * 256;
    ushort* bufAU = bufBase;
    ushort* bufBU = bufBase + (size_t)g * sElems;
    ushort* bufA = bufAU + 256;                        // data row 0 (guard at underlying 0)
    ushort* bufB = bufBU + 256;

    mod_k<<<64, 256, 0, stream>>>(style, weights, mod_w, mod_b, s_all, demod_all);
    wprep_k<<<dim3(256, 4), 256, 0, stream>>>(weights, Wbf);

    for (int b0 = 0; b0 < NB; b0 += g) {
        int gb = NB - b0 < g ? NB - b0 : g;

        // T0 = bf16(x*s0) -> bufA ; guards at data {-1,4096} = underlying {0,4097}
        xprep_k<<<dim3(64, 4, gb), 256, 0, stream>>>(
            x + (size_t)b0 * CIN * 4096, s_all + 0 * SL + b0 * CIN, bufA);
        guard_k<<<gb, 256, 0, stream>>>(bufAU, 0, 4097);

        // conv0 (same, L=4096): bufA -> bufB = T1 (post = dm1*KSCALE folded)
        conv_same_mfma<<<dim3(16, 4, gb), 512, 0, stream>>>(
            bufA, Wbf + 0 * 196608,
            demod_all + 0 * SL + b0 * CIN, demod_all + 1 * SL + b0 * CIN,
            biases + 0 * COUT, bufB);
        guard_k<<<gb, 256, 0, stream>>>(bufBU, 0, 4097);

        // upconv: bufB -> bufA = T2 (8193 data rows)
        upconv_mfma<<<dim3(33, 4, gb), 256, 0, stream>>>(
            bufB, 8193, Wbf + 1 * 196608,
            s_all + 1 * SL + b0 * CIN, biases + 1 * COUT, bufA);

        // blur1 (2*bk, pad 1), fold s2: T2(bufA) -> T3(bufB, 8192 rows); guards {-1,8192}
        blur_bf16_k<<<dim3(1024, gb), 256, 0, stream>>>(
            bufA, 8193, bufB, 8192, s_all + 2 * SL + b0 * CIN,
            1, 0.25f, 0.75f, 0.75f, 0.25f);
        guard_k<<<gb, 256, 0, stream>>>(bufBU, 0, 8193);

        // conv2 (same, L=8192): T3(bufB) -> T4(bufA), no post
        conv_same_mfma<<<dim3(32, 4, gb), 512, 0, stream>>>(
            bufB, Wbf + 2 * 196608,
            demod_all + 2 * SL + b0 * CIN, (const float*)nullptr,
            biases + 2 * COUT, bufA);

        // blur2 (bk, pad 2), fold s3: T4(bufA) -> T5(bufB, 8193 rows)
        blur_bf16_k<<<dim3(1025, gb), 256, 0, stream>>>(
            bufA, 8192, bufB, 8193, s_all + 3 * SL + b0 * CIN,
            2, 0.125f, 0.375f, 0.375f, 0.125f);

        // conv3 (down): T5(bufB) -> out f32 [b][co][4096]
        conv_down_mfma<<<dim3(64, 4, gb), 256, 0, stream>>>(
            bufB, Wbf + 3 * 196608,
            demod_all + 3 * SL + b0 * CIN, biases + 3 * COUT,
            out + (size_t)b0 * COUT * 4096);
    }
}

// Round 11
// 301.964 us; speedup vs baseline: 11.2856x; 1.0371x over previous
//
#include <hip/hip_runtime.h>
#include <math.h>
#include <stddef.h>

#define CIN 256
#define COUT 256
#define SD 512
#define NB 16
#define KSCALE (1.0f / 48.0f)   // 1/sqrt(256*9)
#define MEPS 1e-8f
#define SRROW 8320               // per-sample row stride (rows of 256 bf16)

typedef __attribute__((ext_vector_type(8))) short short8;
typedef __attribute__((ext_vector_type(4))) float floatx4;
typedef unsigned short ushort;

__device__ inline ushort f2bf(float f) {
    union { float f; unsigned int u; } v; v.f = f;
    unsigned int u = v.u;
    return (ushort)((u + 0x7FFFu + ((u >> 16) & 1u)) >> 16);
}
__device__ inline float bf2f(ushort h) {
    union { unsigned int u; float f; } v; v.u = ((unsigned int)h) << 16;
    return v.f;
}

// async global->LDS, 16B per lane; LDS dest is wave-uniform base + lane*16
__device__ inline void gload16(const ushort* g, ushort* l) {
    __builtin_amdgcn_global_load_lds(
        (const __attribute__((address_space(1))) unsigned int*)g,
        (__attribute__((address_space(3))) unsigned int*)l,
        16, 0, 0);
}

// ---------------- modulation (verified round 4-10) ----------------
__global__ __launch_bounds__(256) void mod_k(
    const float* __restrict__ style, const float* __restrict__ weights,
    const float* __restrict__ mod_w, const float* __restrict__ mod_b,
    float* __restrict__ s_all, float* __restrict__ demod_all)
{
    int layer = blockIdx.x >> 4;
    int b = blockIdx.x & 15;
    int t = threadIdx.x;
    __shared__ float st[SD];
    __shared__ float s2[CIN];

    for (int j = t; j < SD; j += 256) st[j] = style[b * SD + j];
    __syncthreads();

    const float* mw = mod_w + ((size_t)layer * CIN + t) * SD;
    float acc = 0.f;
    for (int j = 0; j < SD; ++j) acc += mw[j] * st[j];
    float s = acc + mod_b[layer * CIN + t];
    s_all[((size_t)layer * NB + b) * CIN + t] = s;
    s2[t] = s * s;
    __syncthreads();

    const float* wr = weights + ((size_t)layer * COUT + t) * (CIN * 3);
    float d = 0.f;
    for (int ci = 0; ci < CIN; ++ci) {
        float w0 = wr[ci * 3 + 0], w1 = wr[ci * 3 + 1], w2 = wr[ci * 3 + 2];
        d += (w0 * w0 + w1 * w1 + w2 * w2) * s2[ci];
    }
    demod_all[((size_t)layer * NB + b) * CIN + t] = rsqrtf(KSCALE * KSCALE * d + MEPS);
}

// ---------------- weight prep (verified round 7-10) ----------------
__global__ __launch_bounds__(256) void wprep_k(
    const float* __restrict__ weights, ushort* __restrict__ Wbf)
{
    int layer = blockIdx.y;
    int idx = blockIdx.x * 256 + threadIdx.x;
    int a = idx >> 8, c = idx & 255;
    ushort* wl = Wbf + (size_t)layer * 196608;
    if (layer == 1) {
        const float* src = weights + ((size_t)1 * 196608) + ((size_t)c * 256 + a) * 3;
        #pragma unroll
        for (int k = 0; k < 3; ++k)
            wl[(size_t)k * 65536 + a * 256 + c] = f2bf(src[k]);
    } else {
        const float* src = weights + ((size_t)layer * 196608) + ((size_t)a * 256 + c) * 3;
        #pragma unroll
        for (int k = 0; k < 3; ++k)
            wl[(size_t)a * 768 + k * 256 + c] = f2bf(src[k]);
    }
}

// ---------------- x prep (verified round 7-10) ----------------
__global__ __launch_bounds__(256) void xprep_k(
    const float* __restrict__ x, const float* __restrict__ s0,
    ushort* __restrict__ Tout)
{
    __shared__ ushort lt[64 * 72];
    int l0 = blockIdx.x * 64, ci0 = blockIdx.y * 64;
    int b = blockIdx.z;
    int t = threadIdx.x;
    const float* xb = x + (size_t)b * CIN * 4096;
    const float* sb = s0 + b * CIN;

    for (int idx = t; idx < 64 * 64; idx += 256) {
        int ci = idx >> 6, lc = idx & 63;
        float v = xb[(size_t)(ci0 + ci) * 4096 + l0 + lc] * sb[ci0 + ci];
        lt[lc * 72 + ci] = f2bf(v);
    }
    __syncthreads();
    ushort* ob = Tout + (size_t)b * SRROW * 256;
    for (int idx = t; idx < 64 * 8; idx += 256) {
        int lc = idx >> 3, ch = idx & 7;
        short8 v = *(const short8*)&lt[lc * 72 + ch * 8];
        *(short8*)&ob[(size_t)(l0 + lc) * 256 + ci0 + ch * 8] = v;
    }
}

// ---------------- zero guard rows (UNDERLYING coords; verified) -----------
__global__ __launch_bounds__(256) void guard_k(
    ushort* __restrict__ T, int rowA, int rowB)
{
    int b = blockIdx.x;
    ushort* base = T + (size_t)b * SRROW * 256;
    base[(size_t)rowA * 256 + threadIdx.x] = 0;
    base[(size_t)rowB * 256 + threadIdx.x] = 0;
}

// ---------------- bf16 blur (channel-last) + per-ci scale fold (verified) ---
__global__ __launch_bounds__(256) void blur_bf16_k(
    const ushort* __restrict__ in, int Lin,
    ushort* __restrict__ outp, int Lout,
    const float* __restrict__ scale,   // [b][256]
    int pad, float c0, float c1, float c2, float c3)
{
    int b = blockIdx.y;
    int idx = blockIdx.x * 256 + threadIdx.x;
    if (idx >= Lout * 32) return;
    int row = idx >> 5, ci = (idx & 31) * 8;
    const ushort* ib = in + (size_t)b * SRROW * 256;
    float acc[8] = {};
    int base = row - pad;
    float cf[4] = {c0, c1, c2, c3};
    #pragma unroll
    for (int i = 0; i < 4; ++i) {
        int r = base + i;
        if (r >= 0 && r < Lin) {
            short8 v = *(const short8*)&ib[(size_t)r * 256 + ci];
            #pragma unroll
            for (int j = 0; j < 8; ++j) acc[j] += cf[i] * bf2f((ushort)v[j]);
        }
    }
    short8 o;
    #pragma unroll
    for (int j = 0; j < 8; ++j) {
        float sv = scale[b * CIN + ci + j];
        o[j] = (short)f2bf(acc[j] * sv);
    }
    *(short8*)&outp[((size_t)b * SRROW + row) * 256 + ci] = o;
}

// ================= conv same: 512 threads, 64co x 256l, gload_lds (verified r10) ======
__global__ __launch_bounds__(512, 4) void conv_same_mfma(
    const ushort* __restrict__ Tin,
    const ushort* __restrict__ Wl,      // [co][768]
    const float* __restrict__ dm, const float* __restrict__ post,
    const float* __restrict__ bias,
    ushort* __restrict__ Tout)
{
    __shared__ __align__(16) ushort S[29184];   // Xs 264x64 (16896) | Ws 192x64 (12288)
    ushort* Xs = S;
    ushort* Ws = S + 16896;
    int l0 = blockIdx.x * 256;
    int cot = blockIdx.y * 64;
    int b = blockIdx.z;
    int t = threadIdx.x;
    int lane = t & 63, wv = t >> 6;             // 8 waves
    int lr = lane & 15, lg = lane >> 4;
    int lrow = lane >> 3, cg = lane & 7;

    const ushort* Tb = Tin + (size_t)b * SRROW * 256;

    floatx4 acc[4][2];
    #pragma unroll
    for (int i = 0; i < 4; ++i) { acc[i][0] = (floatx4)0.f; acc[i][1] = (floatx4)0.f; }

    for (int ci0 = 0; ci0 < 256; ci0 += 64) {
        __syncthreads();
        for (int i = wv; i < 24; i += 8) {
            int wr = i * 8 + lrow;
            int co = wr & 63, tap = wr >> 6;
            gload16(Wl + (size_t)(cot + co) * 768 + tap * 256 + ci0 + ((cg ^ (co & 7)) * 8),
                    Ws + i * 512);
        }
        for (int i = wv; i < 33; i += 8) {
            int row = i * 8 + lrow;
            gload16(Tb + (ptrdiff_t)(l0 - 1 + row) * 256 + ci0 + ((cg ^ (row & 7)) * 8),
                    Xs + i * 512);
        }
        __syncthreads();
        #pragma unroll
        for (int tap = 0; tap < 3; ++tap)
            #pragma unroll
            for (int kk = 0; kk < 2; ++kk) {
                short8 a[4];
                #pragma unroll
                for (int mf = 0; mf < 4; ++mf)
                    a[mf] = *(const short8*)&Ws[(tap * 64 + mf * 16 + lr) * 64 + ((kk * 32 + lg * 8) ^ ((lr & 7) * 8))];
                short8 bf[2];
                #pragma unroll
                for (int nf = 0; nf < 2; ++nf) {
                    int row = wv * 32 + nf * 16 + lr + tap;
                    bf[nf] = *(const short8*)&Xs[row * 64 + ((kk * 32 + lg * 8) ^ ((row & 7) * 8))];
                }
                #pragma unroll
                for (int mf = 0; mf < 4; ++mf)
                    #pragma unroll
                    for (int nf = 0; nf < 2; ++nf)
                        acc[mf][nf] = __builtin_amdgcn_mfma_f32_16x16x32_bf16(a[mf], bf[nf], acc[mf][nf], 0, 0, 0);
            }
    }

    __syncthreads();
    ushort* Ot = S;   // 256 x 72
    #pragma unroll
    for (int mf = 0; mf < 4; ++mf)
        #pragma unroll
        for (int nf = 0; nf < 2; ++nf)
            #pragma unroll
            for (int rg = 0; rg < 4; ++rg) {
                int lo = wv * 32 + nf * 16 + lr;
                int co = mf * 16 + lg * 4 + rg;
                float dmv = dm[b * COUT + cot + co] * KSCALE;
                float v = acc[mf][nf][rg] * dmv + bias[cot + co];
                if (post) v *= post[b * COUT + cot + co] * KSCALE;
                Ot[lo * 72 + co] = f2bf(v);
            }
    __syncthreads();
    ushort* ob = Tout + (size_t)b * SRROW * 256;
    for (int idx = t; idx < 256 * 8; idx += 512) {
        int lo = idx >> 3, ch = idx & 7;
        short8 v = *(const short8*)&Ot[lo * 72 + ch * 8];
        *(short8*)&ob[(size_t)(l0 + lo) * 256 + cot + ch * 8] = v;
    }
}

// ================= transpose conv stride 2: 512 threads, 64o x 256m, gload_lds ========
__global__ __launch_bounds__(512, 4) void upconv_mfma(
    const ushort* __restrict__ Tin, int Lout,
    const ushort* __restrict__ Wl,      // [tap][o][c]
    const float* __restrict__ s, const float* __restrict__ bias,
    ushort* __restrict__ Tout)
{
    __shared__ __align__(16) ushort S[29184];   // Xs 264x64 | Ws 192x64
    ushort* Xs = S;
    ushort* Ws = S + 16896;
    int m0 = blockIdx.x * 256;
    int ot = blockIdx.y * 64;
    int b = blockIdx.z;
    int t = threadIdx.x;
    int lane = t & 63, wv = t >> 6;             // 8 waves
    int lr = lane & 15, lg = lane >> 4;
    int lrow = lane >> 3, cg = lane & 7;

    const ushort* Tb = Tin + (size_t)b * SRROW * 256;

    floatx4 aE[4][2], aO[4][2];
    #pragma unroll
    for (int i = 0; i < 4; ++i)
        #pragma unroll
        for (int j = 0; j < 2; ++j) { aE[i][j] = (floatx4)0.f; aO[i][j] = (floatx4)0.f; }

    for (int ci0 = 0; ci0 < 256; ci0 += 64) {
        __syncthreads();
        for (int i = wv; i < 24; i += 8) {
            int wr = i * 8 + lrow;
            int o = wr & 63, tap = wr >> 6;
            gload16(Wl + (size_t)tap * 65536 + (size_t)(ot + o) * 256 + ci0 + ((cg ^ (o & 7)) * 8),
                    Ws + i * 512);
        }
        for (int i = wv; i < 33; i += 8) {
            int row = i * 8 + lrow;
            gload16(Tb + (ptrdiff_t)(m0 - 1 + row) * 256 + ci0 + ((cg ^ (row & 7)) * 8),
                    Xs + i * 512);
        }
        __syncthreads();
        #pragma unroll
        for (int kk = 0; kk < 2; ++kk) {
            short8 bm1[2], bm[2];
            #pragma unroll
            for (int nf = 0; nf < 2; ++nf) {
                int r0 = wv * 32 + nf * 16 + lr;       // row r0 = x[m-1], r0+1 = x[m]
                int ci = kk * 32 + lg * 8;
                bm1[nf] = *(const short8*)&Xs[r0 * 64 + (ci ^ ((r0 & 7) * 8))];
                int r1 = r0 + 1;
                bm[nf]  = *(const short8*)&Xs[r1 * 64 + (ci ^ ((r1 & 7) * 8))];
            }
            #pragma unroll
            for (int tap = 0; tap < 3; ++tap) {
                short8 a[4];
                #pragma unroll
                for (int mf = 0; mf < 4; ++mf)
                    a[mf] = *(const short8*)&Ws[(tap * 64 + mf * 16 + lr) * 64 + ((kk * 32 + lg * 8) ^ ((lr & 7) * 8))];
                #pragma unroll
                for (int mf = 0; mf < 4; ++mf)
                    #pragma unroll
                    for (int nf = 0; nf < 2; ++nf) {
                        if (tap == 0) aE[mf][nf] = __builtin_amdgcn_mfma_f32_16x16x32_bf16(a[mf], bm[nf],  aE[mf][nf], 0, 0, 0);
                        if (tap == 2) aE[mf][nf] = __builtin_amdgcn_mfma_f32_16x16x32_bf16(a[mf], bm1[nf], aE[mf][nf], 0, 0, 0);
                        if (tap == 1) aO[mf][nf] = __builtin_amdgcn_mfma_f32_16x16x32_bf16(a[mf], bm[nf],  aO[mf][nf], 0, 0, 0);
                    }
            }
        }
    }

    // epilogue: two 256-row passes (waves 0-3 then 4-7), Ot = 256x72
    ushort* Ot = S;
    ushort* ob = Tout + (size_t)b * SRROW * 256;
    __syncthreads();
    if (wv < 4) {
        #pragma unroll
        for (int mf = 0; mf < 4; ++mf)
            #pragma unroll
            for (int nf = 0; nf < 2; ++nf)
                #pragma unroll
                for (int rg = 0; rg < 4; ++rg) {
                    int mloc = wv * 32 + nf * 16 + lr;   // 0..127
                    int co = mf * 16 + lg * 4 + rg;
                    float sv = s[b * COUT + ot + co];
                    float bi = bias[ot + co];
                    Ot[(2 * mloc) * 72 + co]     = f2bf(aE[mf][nf][rg] * sv + bi);
                    Ot[(2 * mloc + 1) * 72 + co] = f2bf(aO[mf][nf][rg] * sv + bi);
                }
    }
    __syncthreads();
    for (int idx = t; idx < 256 * 8; idx += 512) {
        int lo = idx >> 3, ch = idx & 7;
        int n = 2 * m0 + lo;
        if (n < Lout) {
            short8 v = *(const short8*)&Ot[lo * 72 + ch * 8];
            *(short8*)&ob[(size_t)n * 256 + ot + ch * 8] = v;
        }
    }
    __syncthreads();
    if (wv >= 4) {
        #pragma unroll
        for (int mf = 0; mf < 4; ++mf)
            #pragma unroll
            for (int nf = 0; nf < 2; ++nf)
                #pragma unroll
                for (int rg = 0; rg < 4; ++rg) {
                    int mloc = wv * 32 + nf * 16 + lr;   // 128..255
                    int co = mf * 16 + lg * 4 + rg;
                    float sv = s[b * COUT + ot + co];
                    float bi = bias[ot + co];
                    Ot[(2 * mloc - 256) * 72 + co] = f2bf(aE[mf][nf][rg] * sv + bi);
                    Ot[(2 * mloc - 255) * 72 + co] = f2bf(aO[mf][nf][rg] * sv + bi);
                }
    }
    __syncthreads();
    for (int idx = t; idx < 256 * 8; idx += 512) {
        int lo = idx >> 3, ch = idx & 7;
        int n = 2 * m0 + 256 + lo;
        if (n < Lout) {
            short8 v = *(const short8*)&Ot[lo * 72 + ch * 8];
            *(short8*)&ob[(size_t)n * 256 + ot + ch * 8] = v;
        }
    }
}

// ================= stride-2 conv: 512 threads, 64co x 128l, gload_lds =================
__global__ __launch_bounds__(512, 4) void conv_down_mfma(
    const ushort* __restrict__ Tin,
    const ushort* __restrict__ Wl,      // [co][768]
    const float* __restrict__ dm, const float* __restrict__ bias,
    float* __restrict__ outp)
{
    __shared__ __align__(16) ushort S[29184];   // Xs 264x64 | Ws 192x64
    ushort* Xs = S;
    ushort* Ws = S + 16896;
    int l0 = blockIdx.x * 128;
    int cot = blockIdx.y * 64;
    int b = blockIdx.z;
    int t = threadIdx.x;
    int lane = t & 63, wv = t >> 6;             // 8 waves; wave owns l = l0 + wv*16 + lr
    int lr = lane & 15, lg = lane >> 4;
    int lrow = lane >> 3, cg = lane & 7;

    const ushort* Tb = Tin + (size_t)b * SRROW * 256;

    floatx4 acc[4];
    #pragma unroll
    for (int i = 0; i < 4; ++i) acc[i] = (floatx4)0.f;

    for (int ci0 = 0; ci0 < 256; ci0 += 64) {
        __syncthreads();
        for (int i = wv; i < 24; i += 8) {
            int wr = i * 8 + lrow;
            int co = wr & 63, tap = wr >> 6;
            gload16(Wl + (size_t)(cot + co) * 768 + tap * 256 + ci0 + ((cg ^ (co & 7)) * 8),
                    Ws + i * 512);
        }
        for (int i = wv; i < 33; i += 8) {
            int row = i * 8 + lrow;
            gload16(Tb + (ptrdiff_t)(2 * l0 + row) * 256 + ci0 + ((cg ^ (row & 7)) * 8),
                    Xs + i * 512);
        }
        __syncthreads();
        #pragma unroll
        for (int tap = 0; tap < 3; ++tap)
            #pragma unroll
            for (int kk = 0; kk < 2; ++kk) {
                short8 a[4];
                #pragma unroll
                for (int mf = 0; mf < 4; ++mf)
                    a[mf] = *(const short8*)&Ws[(tap * 64 + mf * 16 + lr) * 64 + ((kk * 32 + lg * 8) ^ ((lr & 7) * 8))];
                int row = 2 * (wv * 16 + lr) + tap;
                short8 bf = *(const short8*)&Xs[row * 64 + ((kk * 32 + lg * 8) ^ ((row & 7) * 8))];
                #pragma unroll
                for (int mf = 0; mf < 4; ++mf)
                    acc[mf] = __builtin_amdgcn_mfma_f32_16x16x32_bf16(a[mf], bf, acc[mf], 0, 0, 0);
            }
    }

    float* ob = outp + (size_t)b * COUT * 4096;
    #pragma unroll
    for (int mf = 0; mf < 4; ++mf)
        #pragma unroll
        for (int rg = 0; rg < 4; ++rg) {
            int co = cot + mf * 16 + lg * 4 + rg;
            int l = l0 + wv * 16 + lr;
            float dmv = dm[b * COUT + co] * KSCALE;
            ob[(size_t)co * 4096 + l] = acc[mf][rg] * dmv + bias[co];
        }
}

extern "C" void kernel_launch(void* const* d_in, const int* in_sizes, int n_in,
                              void* d_out, int out_size, void* d_ws, size_t ws_size,
                              hipStream_t stream) {
    const float* x       = (const float*)d_in[0];
    const float* style   = (const float*)d_in[1];
    const float* weights = (const float*)d_in[2];
    const float* biases  = (const float*)d_in[3];
    const float* mod_w   = (const float*)d_in[4];
    const float* mod_b   = (const float*)d_in[5];
    float* out = (float*)d_out;

    float* s_all = (float*)d_ws;                       // 4*16*256
    float* demod_all = s_all + 4 * NB * CIN;           // 4*16*256
    const size_t WBF_OFF = 131072;                     // bytes
    const size_t BUF_OFF = WBF_OFF + 1572864;          // + Wbf bytes
    ushort* Wbf = (ushort*)((char*)d_ws + WBF_OFF);
    ushort* bufBase = (ushort*)((char*)d_ws + BUF_OFF);

    const int SL = NB * CIN;
    const size_t perSampleB = (size_t)2 * SRROW * 256 * sizeof(ushort);
    size_t availB = ws_size > BUF_OFF ? ws_size - BUF_OFF : 0;
    int g = (int)(availB / perSampleB);
    if (g < 1) g = 1;
    if (g > NB) g = NB;

    const size_t sElems = (size_t)SRROW * 256;
    ushort* bufAU = bufBase;
    ushort* bufBU = bufBase + (size_t)g * sElems;
    ushort* bufA = bufAU + 256;                        // data row 0 (guard at underlying 0)
    ushort* bufB = bufBU + 256;

    mod_k<<<64, 256, 0, stream>>>(style, weights, mod_w, mod_b, s_all, demod_all);
    wprep_k<<<dim3(256, 4), 256, 0, stream>>>(weights, Wbf);

    for (int b0 = 0; b0 < NB; b0 += g) {
        int gb = NB - b0 < g ? NB - b0 : g;

        // T0 = bf16(x*s0) -> bufA ; guards at data {-1,4096} = underlying {0,4097}
        xprep_k<<<dim3(64, 4, gb), 256, 0, stream>>>(
            x + (size_t)b0 * CIN * 4096, s_all + 0 * SL + b0 * CIN, bufA);
        guard_k<<<gb, 256, 0, stream>>>(bufAU, 0, 4097);

        // conv0 (same, L=4096): bufA -> bufB = T1 (post = dm1*KSCALE folded)
        conv_same_mfma<<<dim3(16, 4, gb), 512, 0, stream>>>(
            bufA, Wbf + 0 * 196608,
            demod_all + 0 * SL + b0 * CIN, demod_all + 1 * SL + b0 * CIN,
            biases + 0 * COUT, bufB);
        guard_k<<<gb, 256, 0, stream>>>(bufBU, 0, 4097);

        // upconv: bufB -> bufA = T2 (8193 data rows)
        upconv_mfma<<<dim3(17, 4, gb), 512, 0, stream>>>(
            bufB, 8193, Wbf + 1 * 196608,
            s_all + 1 * SL + b0 * CIN, biases + 1 * COUT, bufA);

        // blur1 (2*bk, pad 1), fold s2: T2(bufA) -> T3(bufB, 8192 rows); guards {-1,8192}
        blur_bf16_k<<<dim3(1024, gb), 256, 0, stream>>>(
            bufA, 8193, bufB, 8192, s_all + 2 * SL + b0 * CIN,
            1, 0.25f, 0.75f, 0.75f, 0.25f);
        guard_k<<<gb, 256, 0, stream>>>(bufBU, 0, 8193);

        // conv2 (same, L=8192): T3(bufB) -> T4(bufA), no post
        conv_same_mfma<<<dim3(32, 4, gb), 512, 0, stream>>>(
            bufB, Wbf + 2 * 196608,
            demod_all + 2 * SL + b0 * CIN, (const float*)nullptr,
            biases + 2 * COUT, bufA);

        // blur2 (bk, pad 2), fold s3: T4(bufA) -> T5(bufB, 8193 rows)
        blur_bf16_k<<<dim3(1025, gb), 256, 0, stream>>>(
            bufA, 8192, bufB, 8193, s_all + 3 * SL + b0 * CIN,
            2, 0.125f, 0.375f, 0.375f, 0.125f);

        // conv3 (down): T5(bufB) -> out f32 [b][co][4096]
        conv_down_mfma<<<dim3(32, 4, gb), 512, 0, stream>>>(
            bufB, Wbf + 3 * 196608,
            demod_all + 3 * SL + b0 * CIN, biases + 3 * COUT,
            out + (size_t)b0 * COUT * 4096);
    }
}